// Round 10
// baseline (1298.829 us; speedup 1.0000x reference)
//
#include <hip/hip_runtime.h>
#include <math.h>

static const int NA = 20000;
static const int NE = 320000;
static const int F  = 128;
static const long NF = (long)NA * F;   // 2,560,000

typedef short short8 __attribute__((ext_vector_type(8)));   // 8 bf16 (4 VGPRs)
typedef float f32x4  __attribute__((ext_vector_type(4)));

// ---------------------------------------------------------------- geometry (+ fused hist)
__global__ void geom_kernel(const float* __restrict__ xyz, const int* __restrict__ nbrs,
                            float* __restrict__ edata, int* __restrict__ act,
                            int* __restrict__ cnt) {
    int e = blockIdx.x * 256 + threadIdx.x;
    if (e >= NE) return;
    int i = nbrs[2 * e], j = nbrs[2 * e + 1];
    float xi = xyz[3 * i], yi = xyz[3 * i + 1], zi = xyz[3 * i + 2];
    float xj = xyz[3 * j], yj = xyz[3 * j + 1], zj = xyz[3 * j + 2];
    float rx = xj - xi, ry = yj - yi, rz = zj - zi;
    float d2 = rx * rx + ry * ry + rz * rz + 1e-15f;
    float d = sqrtf(d2);
    if (d >= 5.0f) { act[e] = 0; return; }
    act[e] = 1;
    atomicAdd(&cnt[i], 1);
    float inv = 1.0f / d;
    float fc = 0.5f * (cosf(d * (float)M_PI / 5.0f) + 1.0f);
    float* ed = edata + (size_t)e * 24;
    ed[0] = fc; ed[1] = rx * inv; ed[2] = ry * inv; ed[3] = rz * inv;
    float x = d * (float)M_PI / 5.0f;
    float s1 = sinf(x), c1 = cosf(x);
    float skm1 = 0.f, sk = s1;
    float twoc = 2.f * c1;
    float scale = inv * fc;
    #pragma unroll
    for (int k = 0; k < 20; k++) {
        ed[4 + k] = sk * scale;
        float skp1 = twoc * sk - skm1;
        skm1 = sk; sk = skp1;
    }
}

// ---------------------------------------------------------------- CSR build (active edges only)
__global__ __launch_bounds__(1024) void scan_kernel(const int* __restrict__ cnt, int* __restrict__ offs) {
    __shared__ int sh[1024];
    const int CH = 20;
    int t = threadIdx.x;
    int base = t * CH;
    int c[CH];
    int tot = 0;
    #pragma unroll
    for (int k = 0; k < CH; k++) {
        int idx = base + k;
        c[k] = (idx < NA) ? cnt[idx] : 0;
        tot += c[k];
    }
    sh[t] = tot;
    __syncthreads();
    for (int o = 1; o < 1024; o <<= 1) {
        int v = (t >= o) ? sh[t - o] : 0;
        __syncthreads();
        sh[t] += v;
        __syncthreads();
    }
    int run = sh[t] - tot;
    #pragma unroll
    for (int k = 0; k < CH; k++) {
        int idx = base + k;
        if (idx < NA) offs[idx] = run;
        run += c[k];
    }
    if (t == 1023) offs[NA] = sh[1023];
}

__global__ void fill_kernel(const int* __restrict__ nbrs, const int* __restrict__ act,
                            const int* __restrict__ offs, int* __restrict__ cur,
                            const float* __restrict__ edata,
                            int* __restrict__ jc, float* __restrict__ edc) {
    int e = blockIdx.x * 256 + threadIdx.x;
    if (e >= NE || !act[e]) return;
    int i = nbrs[2 * e];
    int q = offs[i] + atomicAdd(&cur[i], 1);
    jc[q] = nbrs[2 * e + 1];
    const float4* src = (const float4*)(edata + (size_t)e * 24);
    float4* dst = (float4*)(edc + (size_t)q * 24);
    #pragma unroll
    for (int k = 0; k < 6; k++) dst[k] = src[k];
}

// ---------------------------------------------------------------- embed (+ split)
__global__ void embed_kernel(const int* __restrict__ z, const float* __restrict__ embed,
                             float* __restrict__ s, __bf16* __restrict__ sh_, __bf16* __restrict__ sl_) {
    int idx = blockIdx.x * 256 + threadIdx.x;
    if (idx >= NA * F) return;
    int n = idx >> 7, f = idx & 127;
    float v = embed[z[n] * F + f];
    s[idx] = v;
    __bf16 h = (__bf16)v;
    sh_[idx] = h; sl_[idx] = (__bf16)(v - (float)h);
}

// ---------------------------------------------------------------- weight transpose + split
static const int WSEG = 180224;
static const int WRO  = 3 * WSEG;        // 540672
static const int WTOT = WRO + 36864;     // 577536

__global__ void wconv_kernel(const float* __restrict__ W1, const float* __restrict__ W2,
                             const float* __restrict__ U, const float* __restrict__ V,
                             const float* __restrict__ Ws1, const float* __restrict__ Ws2,
                             const float* __restrict__ roW1, const float* __restrict__ roW2,
                             const float* __restrict__ fcW1, const float* __restrict__ fcW2,
                             __bf16* __restrict__ wh, __bf16* __restrict__ wl) {
    int g = blockIdx.x * 256 + threadIdx.x;
    if (g >= WTOT) return;
    const float* src; int K, N, idx;
    if (g < WRO) {
        int lay = g / WSEG, o = g - lay * WSEG;
        if (o < 16384)       { src = W1  + (size_t)lay * 16384; K = 128; N = 128; idx = o; }
        else if (o < 65536)  { src = W2  + (size_t)lay * 49152; K = 128; N = 384; idx = o - 16384; }
        else if (o < 81920)  { src = U   + (size_t)lay * 16384; K = 128; N = 128; idx = o - 65536; }
        else if (o < 98304)  { src = V   + (size_t)lay * 16384; K = 128; N = 128; idx = o - 81920; }
        else if (o < 131072) { src = Ws1 + (size_t)lay * 32768; K = 256; N = 128; idx = o - 98304; }
        else                 { src = Ws2 + (size_t)lay * 49152; K = 128; N = 384; idx = o - 131072; }
    } else {
        int o2 = g - WRO;
        if (o2 < 8192)       { src = roW1; K = 128; N = 64;  idx = o2; }
        else if (o2 < 12288) { src = roW2; K = 64;  N = 64;  idx = o2 - 8192; }
        else if (o2 < 20480) { src = fcW1; K = 64;  N = 128; idx = o2 - 12288; }
        else                 { src = fcW2; K = 128; N = 128; idx = o2 - 20480; }
    }
    int n = idx / K, k = idx - n * K;
    float v = src[(size_t)k * N + n];
    __bf16 h = (__bf16)v;
    wh[g] = h; wl[g] = (__bf16)(v - (float)h);
}

// ---------------------------------------------------------------- split-bf16 MFMA GEMM
// 128x128 tile, BK=64, 512 threads / 8 waves (2 row-halves x 4 col-quarters),
// 16x16x32 MFMA, 3 products (hh, hl, lh). Per-wave sub-tile 64x32 (acc 4x2).
// LDS: 4 comps x [128][64] bf16 = 64KB -> 2 blocks/CU = 16 waves/CU.
// Write-side XOR swizzle slot^=row&7, same involution on read.
template<int ACT, int MODE>   // ACT: 0 none, 1 silu, 2 relu. MODE: 0 f32 out, 1 split bf16 out
__device__ __forceinline__ void mgemm_body(char* ldsb,
    const __bf16* __restrict__ Ah, const __bf16* __restrict__ Al,
    const __bf16* __restrict__ Bh, const __bf16* __restrict__ Bl,
    const float* __restrict__ bias, int K, int N, int c0,
    float* __restrict__ Cf, __bf16* __restrict__ Ch, __bf16* __restrict__ Cl) {
    int tid = threadIdx.x;
    int w = tid >> 6, l = tid & 63;
    int r0 = blockIdx.x * 128;

    int srow = tid >> 3, sl = tid & 7;            // srow in [0,64)

    int wr = w >> 2, wc = w & 3;                  // 2 x 4 wave grid
    int lrow = l & 15, lk = l >> 4;
    uint32_t arow[4], axor[4], brow[2], bxor[2];
    #pragma unroll
    for (int m = 0; m < 4; m++) {
        int row = wr * 64 + m * 16 + lrow;
        arow[m] = (uint32_t)row * 128u; axor[m] = (uint32_t)((row & 7) << 4);
    }
    #pragma unroll
    for (int n = 0; n < 2; n++) {
        int row = wc * 32 + n * 16 + lrow;
        brow[n] = (uint32_t)row * 128u; bxor[n] = (uint32_t)((row & 7) << 4);
    }

    f32x4 acc[4][2];
    #pragma unroll
    for (int m = 0; m < 4; m++)
        #pragma unroll
        for (int n = 0; n < 2; n++) acc[m][n] = (f32x4){0.f, 0.f, 0.f, 0.f};

    const char* pAh = (const char*)Ah;
    const char* pAl = (const char*)Al;
    const char* pBh = (const char*)Bh;
    const char* pBl = (const char*)Bl;

    for (int k0 = 0; k0 < K; k0 += 64) {
        #pragma unroll
        for (int t = 0; t < 2; t++) {
            int row = srow + t * 64;
            uint32_t dst = (uint32_t)row * 128u + (uint32_t)(((sl ^ (row & 7)) << 4));
            int ga = min(r0 + row, NA - 1);
            int gb = min(c0 + row, N - 1);
            size_t soA = ((size_t)ga * K + k0 + sl * 8) * 2;
            size_t soB = ((size_t)gb * K + k0 + sl * 8) * 2;
            *(float4*)(ldsb + dst)         = *(const float4*)(pAh + soA);
            *(float4*)(ldsb + 16384 + dst) = *(const float4*)(pAl + soA);
            *(float4*)(ldsb + 32768 + dst) = *(const float4*)(pBh + soB);
            *(float4*)(ldsb + 49152 + dst) = *(const float4*)(pBl + soB);
        }
        __syncthreads();
        #pragma unroll
        for (int kh = 0; kh < 2; kh++) {
            uint32_t ks = (uint32_t)((kh * 4 + lk) * 16);
            short8 fah[4], fal[4], fbh[2], fbl[2];
            #pragma unroll
            for (int m = 0; m < 4; m++) {
                uint32_t ob = arow[m] + (ks ^ axor[m]);
                fah[m] = *(const short8*)(ldsb + ob);
                fal[m] = *(const short8*)(ldsb + 16384 + ob);
            }
            #pragma unroll
            for (int n = 0; n < 2; n++) {
                uint32_t ob = brow[n] + (ks ^ bxor[n]);
                fbh[n] = *(const short8*)(ldsb + 32768 + ob);
                fbl[n] = *(const short8*)(ldsb + 49152 + ob);
            }
            #pragma unroll
            for (int m = 0; m < 4; m++)
                #pragma unroll
                for (int n = 0; n < 2; n++) {
                    acc[m][n] = __builtin_amdgcn_mfma_f32_16x16x32_bf16(fah[m], fbh[n], acc[m][n], 0, 0, 0);
                    acc[m][n] = __builtin_amdgcn_mfma_f32_16x16x32_bf16(fah[m], fbl[n], acc[m][n], 0, 0, 0);
                    acc[m][n] = __builtin_amdgcn_mfma_f32_16x16x32_bf16(fal[m], fbh[n], acc[m][n], 0, 0, 0);
                }
        }
        __syncthreads();
    }

    // epilogue: C col = lane&15, row = (lane>>4)*4 + reg (m89-verified)
    #pragma unroll
    for (int n = 0; n < 2; n++) {
        int gc = c0 + wc * 32 + n * 16 + lrow;
        float bb = (bias && gc < N) ? bias[gc] : 0.f;
        #pragma unroll
        for (int m = 0; m < 4; m++) {
            #pragma unroll
            for (int r = 0; r < 4; r++) {
                int gr = r0 + wr * 64 + m * 16 + lk * 4 + r;
                if (gr < NA && gc < N) {
                    float y = acc[m][n][r] + bb;
                    if (ACT == 1) y = y / (1.f + expf(-y));
                    if (ACT == 2) y = fmaxf(y, 0.f);
                    if (MODE == 0) {
                        Cf[(size_t)gr * N + gc] = y;
                    } else {
                        __bf16 h = (__bf16)y;
                        Ch[(size_t)gr * N + gc] = h;
                        Cl[(size_t)gr * N + gc] = (__bf16)(y - (float)h);
                    }
                }
            }
        }
    }
}

template<int ACT, int MODE>
__global__ __launch_bounds__(512, 4) void mgemm_kernel(
    const __bf16* __restrict__ Ah, const __bf16* __restrict__ Al,
    const __bf16* __restrict__ Bh, const __bf16* __restrict__ Bl,
    const float* __restrict__ bias, int K, int N,
    float* __restrict__ Cf, __bf16* __restrict__ Ch, __bf16* __restrict__ Cl) {
    __shared__ __attribute__((aligned(16))) char lds[65536];
    mgemm_body<ACT, MODE>(lds, Ah, Al, Bh, Bl, bias, K, N, blockIdx.y * 128, Cf, Ch, Cl);
}

// u_v / v_v batched: grid.z = 6 -> (mat = z/3 in {U,V}, d = z%3); fp32 out
__global__ __launch_bounds__(512, 4) void mgemm_uvvv_kernel(
    const __bf16* __restrict__ vBh, const __bf16* __restrict__ vBl,
    const __bf16* __restrict__ Uth, const __bf16* __restrict__ Utl,
    const __bf16* __restrict__ Vth, const __bf16* __restrict__ Vtl,
    float* __restrict__ uv, float* __restrict__ vv) {
    __shared__ __attribute__((aligned(16))) char lds[65536];
    int zz = blockIdx.z, d = zz % 3;
    const __bf16* Ah = vBh + (size_t)d * NF;
    const __bf16* Al = vBl + (size_t)d * NF;
    const __bf16* Bh = (zz < 3) ? Uth : Vth;
    const __bf16* Bl = (zz < 3) ? Utl : Vtl;
    float* Cf = ((zz < 3) ? uv : vv) + (size_t)d * NF;
    mgemm_body<0, 0>(lds, Ah, Al, Bh, Bl, nullptr, 128, 128, 0, Cf, nullptr, nullptr);
}

// Ws1 GEMM with fused "stack": A cols 0-127 = s (split, POST-message), cols
// 128-255 = vnorm computed on the fly from fp32 vv. K=256, N=128, silu, split out.
__global__ __launch_bounds__(512, 4) void mgemm_ws1_kernel(
    const __bf16* __restrict__ sh_, const __bf16* __restrict__ sl_,
    const float* __restrict__ vv,
    const __bf16* __restrict__ Bh, const __bf16* __restrict__ Bl,
    const float* __restrict__ bias,
    __bf16* __restrict__ Ch, __bf16* __restrict__ Cl) {
    __shared__ __attribute__((aligned(16))) char ldsb[65536];
    const int K = 256, N = 128;
    int tid = threadIdx.x;
    int w = tid >> 6, l = tid & 63;
    int r0 = blockIdx.x * 128;
    int srow = tid >> 3, sl = tid & 7;
    int wr = w >> 2, wc = w & 3;
    int lrow = l & 15, lk = l >> 4;
    uint32_t arow[4], axor[4], brow[2], bxor[2];
    #pragma unroll
    for (int m = 0; m < 4; m++) {
        int row = wr * 64 + m * 16 + lrow;
        arow[m] = (uint32_t)row * 128u; axor[m] = (uint32_t)((row & 7) << 4);
    }
    #pragma unroll
    for (int n = 0; n < 2; n++) {
        int row = wc * 32 + n * 16 + lrow;
        brow[n] = (uint32_t)row * 128u; bxor[n] = (uint32_t)((row & 7) << 4);
    }
    f32x4 acc[4][2];
    #pragma unroll
    for (int m = 0; m < 4; m++)
        #pragma unroll
        for (int n = 0; n < 2; n++) acc[m][n] = (f32x4){0.f, 0.f, 0.f, 0.f};

    for (int k0 = 0; k0 < K; k0 += 64) {
        #pragma unroll
        for (int t = 0; t < 2; t++) {
            int row = srow + t * 64;
            uint32_t dst = (uint32_t)row * 128u + (uint32_t)(((sl ^ (row & 7)) << 4));
            int ga = min(r0 + row, NA - 1);
            int gb = row;   // N=128 weight rows
            size_t soB = ((size_t)gb * K + k0 + sl * 8) * 2;
            *(float4*)(ldsb + 32768 + dst) = *(const float4*)((const char*)Bh + soB);
            *(float4*)(ldsb + 49152 + dst) = *(const float4*)((const char*)Bl + soB);
            if (k0 < 128) {
                size_t soA = ((size_t)ga * 128 + k0 + sl * 8) * 2;
                *(float4*)(ldsb + dst)         = *(const float4*)((const char*)sh_ + soA);
                *(float4*)(ldsb + 16384 + dst) = *(const float4*)((const char*)sl_ + soA);
            } else {
                int f0 = (k0 - 128) + sl * 8;
                size_t b = (size_t)ga * 128 + f0;
                float4 a0 = *(const float4*)(vv + b);
                float4 a1 = *(const float4*)(vv + b + 4);
                float4 b0 = *(const float4*)(vv + NF + b);
                float4 b1 = *(const float4*)(vv + NF + b + 4);
                float4 c0v = *(const float4*)(vv + 2 * NF + b);
                float4 c1v = *(const float4*)(vv + 2 * NF + b + 4);
                float xs[8] = {a0.x, a0.y, a0.z, a0.w, a1.x, a1.y, a1.z, a1.w};
                float ys[8] = {b0.x, b0.y, b0.z, b0.w, b1.x, b1.y, b1.z, b1.w};
                float zs[8] = {c0v.x, c0v.y, c0v.z, c0v.w, c1v.x, c1v.y, c1v.z, c1v.w};
                union { short8 s; float4 q; } hi, lo;
                #pragma unroll
                for (int k = 0; k < 8; k++) {
                    float vn = sqrtf(xs[k] * xs[k] + ys[k] * ys[k] + zs[k] * zs[k] + 1e-15f);
                    __bf16 h = (__bf16)vn;
                    hi.s[k] = *(short*)&h;
                    __bf16 lo_b = (__bf16)(vn - (float)h);
                    lo.s[k] = *(short*)&lo_b;
                }
                *(float4*)(ldsb + dst)         = hi.q;
                *(float4*)(ldsb + 16384 + dst) = lo.q;
            }
        }
        __syncthreads();
        #pragma unroll
        for (int kh = 0; kh < 2; kh++) {
            uint32_t ks = (uint32_t)((kh * 4 + lk) * 16);
            short8 fah[4], fal[4], fbh[2], fbl[2];
            #pragma unroll
            for (int m = 0; m < 4; m++) {
                uint32_t ob = arow[m] + (ks ^ axor[m]);
                fah[m] = *(const short8*)(ldsb + ob);
                fal[m] = *(const short8*)(ldsb + 16384 + ob);
            }
            #pragma unroll
            for (int n = 0; n < 2; n++) {
                uint32_t ob = brow[n] + (ks ^ bxor[n]);
                fbh[n] = *(const short8*)(ldsb + 32768 + ob);
                fbl[n] = *(const short8*)(ldsb + 49152 + ob);
            }
            #pragma unroll
            for (int m = 0; m < 4; m++)
                #pragma unroll
                for (int n = 0; n < 2; n++) {
                    acc[m][n] = __builtin_amdgcn_mfma_f32_16x16x32_bf16(fah[m], fbh[n], acc[m][n], 0, 0, 0);
                    acc[m][n] = __builtin_amdgcn_mfma_f32_16x16x32_bf16(fah[m], fbl[n], acc[m][n], 0, 0, 0);
                    acc[m][n] = __builtin_amdgcn_mfma_f32_16x16x32_bf16(fal[m], fbh[n], acc[m][n], 0, 0, 0);
                }
        }
        __syncthreads();
    }
    #pragma unroll
    for (int n = 0; n < 2; n++) {
        int gc = wc * 32 + n * 16 + lrow;
        float bb = bias[gc];
        #pragma unroll
        for (int m = 0; m < 4; m++) {
            #pragma unroll
            for (int r = 0; r < 4; r++) {
                int gr = r0 + wr * 64 + m * 16 + lk * 4 + r;
                if (gr < NA) {
                    float y = acc[m][n][r] + bb;
                    y = y / (1.f + expf(-y));
                    __bf16 h = (__bf16)y;
                    Ch[(size_t)gr * N + gc] = h;
                    Cl[(size_t)gr * N + gc] = (__bf16)(y - (float)h);
                }
            }
        }
    }
}

// ---------------------------------------------------------------- message + aggregation
// work-stealing persistent blocks: each 128-thread block grabs atoms from a
// global cursor (amortizes the 63-load Wd preload; no degree-tail imbalance).
// Output independent of processing order: per-atom writes are exclusive.
__global__ __launch_bounds__(128) void msg_kernel(
    const float* __restrict__ phi, const float* __restrict__ edc,
    const int* __restrict__ jc, const int* __restrict__ offs,
    const float* __restrict__ Wd, const float* __restrict__ bd,
    const float* __restrict__ vin, float* __restrict__ s,
    __bf16* __restrict__ sh_, __bf16* __restrict__ sl_,
    __bf16* __restrict__ vBh, __bf16* __restrict__ vBl,
    int* __restrict__ cursor) {
    int f = threadIdx.x;
    float wd0[20], wd1[20], wd2[20];
    #pragma unroll
    for (int k = 0; k < 20; k++) {
        wd0[k] = Wd[k * 384 + f];
        wd1[k] = Wd[k * 384 + 128 + f];
        wd2[k] = Wd[k * 384 + 256 + f];
    }
    float b0 = bd[f], b1 = bd[128 + f], b2 = bd[256 + f];
    __shared__ int s_atom;
    for (;;) {
        if (f == 0) s_atom = atomicAdd(cursor, 1);
        __syncthreads();
        int i = s_atom;
        if (i >= NA) break;
        float accS = 0.f, aV0 = 0.f, aV1 = 0.f, aV2 = 0.f;
        int p0 = offs[i], p1 = offs[i + 1];
        for (int p = p0; p < p1; ++p) {
            int j = jc[p];
            const float4* ed = (const float4*)(edc + (size_t)p * 24);
            float4 q0 = ed[0], q1 = ed[1], q2 = ed[2], q3 = ed[3], q4 = ed[4], q5 = ed[5];
            float fc = q0.x, ux = q0.y, uy = q0.z, uz = q0.w;
            float rb[20];
            rb[0]=q1.x; rb[1]=q1.y; rb[2]=q1.z; rb[3]=q1.w;
            rb[4]=q2.x; rb[5]=q2.y; rb[6]=q2.z; rb[7]=q2.w;
            rb[8]=q3.x; rb[9]=q3.y; rb[10]=q3.z; rb[11]=q3.w;
            rb[12]=q4.x; rb[13]=q4.y; rb[14]=q4.z; rb[15]=q4.w;
            rb[16]=q5.x; rb[17]=q5.y; rb[18]=q5.z; rb[19]=q5.w;
            float w0 = b0 * fc, w1 = b1 * fc, w2 = b2 * fc;
            #pragma unroll
            for (int k = 0; k < 20; k++) {
                w0 += rb[k] * wd0[k];
                w1 += rb[k] * wd1[k];
                w2 += rb[k] * wd2[k];
            }
            const float* pj = phi + (size_t)j * 384;
            float i0 = pj[f] * w0, i1 = pj[128 + f] * w1, i2 = pj[256 + f] * w2;
            const float* vj = vin + (size_t)j * 384;
            accS += i1;
            aV0 += i2 * ux + i0 * vj[f];
            aV1 += i2 * uy + i0 * vj[128 + f];
            aV2 += i2 * uz + i0 * vj[256 + f];
        }
        size_t ib = (size_t)i * F + f;
        float ns = s[ib] + accS;
        s[ib] = ns;
        __bf16 hs = (__bf16)ns;
        sh_[ib] = hs; sl_[ib] = (__bf16)(ns - (float)hs);
        const float* vi = vin + (size_t)i * 384;
        float o0 = vi[f] + aV0;
        float o1 = vi[128 + f] + aV1;
        float o2 = vi[256 + f] + aV2;
        __bf16 h0 = (__bf16)o0, h1 = (__bf16)o1, h2 = (__bf16)o2;
        vBh[ib] = h0;            vBl[ib] = (__bf16)(o0 - (float)h0);
        vBh[NF + ib] = h1;       vBl[NF + ib] = (__bf16)(o1 - (float)h1);
        vBh[2 * NF + ib] = h2;   vBl[2 * NF + ib] = (__bf16)(o2 - (float)h2);
        __syncthreads();   // protect s_atom before next grab
    }
}

// ---------------------------------------------------------------- update
__global__ void update_kernel(const float* __restrict__ spl, const float* __restrict__ uv,
                              const float* __restrict__ vv,
                              const __bf16* __restrict__ vBh, const __bf16* __restrict__ vBl,
                              float* __restrict__ vout, float* __restrict__ s,
                              __bf16* __restrict__ sh_, __bf16* __restrict__ sl_) {
    int idx = blockIdx.x * 256 + threadIdx.x;
    if (idx >= NA * F) return;
    int n = idx >> 7, f = idx & 127;
    const float* sp = spl + (size_t)n * 384;
    float avv = sp[f], asv = sp[128 + f], ass = sp[256 + f];
    float dot = 0.f;
    #pragma unroll
    for (int d = 0; d < 3; d++) {
        float u = uv[d * NF + idx];
        float vb = (float)vBh[d * NF + idx] + (float)vBl[d * NF + idx];
        vout[(size_t)n * 384 + d * 128 + f] = vb + u * avv;
        dot += u * vv[d * NF + idx];
    }
    float ns = s[idx] + dot * asv + ass;
    s[idx] = ns;
    __bf16 h = (__bf16)ns;
    sh_[idx] = h; sl_[idx] = (__bf16)(ns - (float)h);
}

// ---------------------------------------------------------------- head
__global__ __launch_bounds__(256) void head_kernel(const float* __restrict__ h,
                                                   const float* __restrict__ Wo,
                                                   const float* __restrict__ bo,
                                                   float* __restrict__ out) {
    int n = blockIdx.x * 4 + (threadIdx.x >> 6);
    int lane = threadIdx.x & 63;
    if (n >= NA) return;
    float p = h[(size_t)n * 128 + lane] * Wo[lane] + h[(size_t)n * 128 + 64 + lane] * Wo[64 + lane];
    #pragma unroll
    for (int o = 32; o > 0; o >>= 1) p += __shfl_down(p, o);
    if (lane == 0) out[n] = p + bo[0];
}

// ---------------------------------------------------------------- host
extern "C" void kernel_launch(void* const* d_in, const int* in_sizes, int n_in,
                              void* d_out, int out_size, void* d_ws, size_t ws_size,
                              hipStream_t stream) {
    const float* xyz    = (const float*)d_in[0];
    const int*   z      = (const int*)d_in[1];
    const int*   nbrs   = (const int*)d_in[2];
    const float* embed  = (const float*)d_in[3];
    const float* msg_W1 = (const float*)d_in[4];
    const float* msg_b1 = (const float*)d_in[5];
    const float* msg_W2 = (const float*)d_in[6];
    const float* msg_b2 = (const float*)d_in[7];
    const float* msg_Wd = (const float*)d_in[8];
    const float* msg_bd = (const float*)d_in[9];
    const float* upd_U  = (const float*)d_in[10];
    const float* upd_V  = (const float*)d_in[11];
    const float* upd_Ws1= (const float*)d_in[12];
    const float* upd_bs1= (const float*)d_in[13];
    const float* upd_Ws2= (const float*)d_in[14];
    const float* upd_bs2= (const float*)d_in[15];
    const float* ro_W1  = (const float*)d_in[16];
    const float* ro_b1  = (const float*)d_in[17];
    const float* ro_W2  = (const float*)d_in[18];
    const float* ro_b2  = (const float*)d_in[19];
    const float* fc_W1  = (const float*)d_in[20];
    const float* fc_b1  = (const float*)d_in[21];
    const float* fc_W2  = (const float*)d_in[22];
    const float* fc_b2  = (const float*)d_in[23];
    const float* fc_Wo  = (const float*)d_in[24];
    const float* fc_bo  = (const float*)d_in[25];
    float* out = (float*)d_out;

    char* ws = (char*)d_ws;
    size_t off = 0;
    auto alloc = [&](size_t nbytes) -> char* {
        char* p = ws + off;
        off += (nbytes + 255) / 256 * 256;
        return p;
    };
    // total ~240.6 MB (R5/R7/R9 passed at this size; 271 faulted)
    float*  edc   = (float*)alloc((size_t)NE * 24 * 4);
    float*  s     = (float*)alloc((size_t)NA * F * 4);
    __bf16* sh_   = (__bf16*)alloc((size_t)NA * F * 2);
    __bf16* sl_   = (__bf16*)alloc((size_t)NA * F * 2);
    float*  vA    = (float*)alloc((size_t)3 * NF * 4);     // interleaved [n][3][128]
    __bf16* vBh   = (__bf16*)alloc((size_t)3 * NF * 2);
    __bf16* vBl   = (__bf16*)alloc((size_t)3 * NF * 2);
    float*  phi   = (float*)alloc((size_t)NA * 384 * 4);   // also spl + readout t4
    __bf16* hid_h = (__bf16*)alloc((size_t)NA * F * 2);    // also t1h
    __bf16* hid_l = (__bf16*)alloc((size_t)NA * F * 2);    // also t1l
    float*  uv    = (float*)alloc((size_t)3 * NF * 4);     // also geometry temp
    float*  vv    = (float*)alloc((size_t)3 * NF * 4);
    __bf16* stkh  = (__bf16*)alloc((size_t)NA * 256 * 2);  // readout t2h
    __bf16* stkl  = (__bf16*)alloc((size_t)NA * 256 * 2);  // readout t2l
    __bf16* wt_h  = (__bf16*)alloc((size_t)WTOT * 2);
    __bf16* wt_l  = (__bf16*)alloc((size_t)WTOT * 2);
    int* act  = (int*)alloc((size_t)NE * 4);
    int* misc = (int*)alloc((size_t)(2 * NA + 8) * 4);     // cnt | cur | msg cursors, one memset
    int* offs = (int*)alloc((size_t)(NA + 1) * 4);
    int* jc   = (int*)alloc((size_t)NE * 4);
    int* cnt = misc;
    int* cur = misc + NA;
    int* mcur = misc + 2 * NA;                             // 3 per-layer cursors

    float* edata = uv;                 // geometry temp (dead before uv first written)
    __bf16* t1h = hid_h, *t1l = hid_l; // readout temps (dead after layers)
    __bf16* t2h = stkh,  *t2l = stkl;
    __bf16* t3h = sh_,   *t3l = sl_;   // sh_ dead after readout gemm1 reads it
    float*  t4  = phi;

    // geometry + active-edge CSR
    hipMemsetAsync(misc, 0, (size_t)(2 * NA + 8) * 4, stream);
    geom_kernel<<<(NE + 255) / 256, 256, 0, stream>>>(xyz, nbrs, edata, act, cnt);
    scan_kernel<<<1, 1024, 0, stream>>>(cnt, offs);
    fill_kernel<<<(NE + 255) / 256, 256, 0, stream>>>(nbrs, act, offs, cur, edata, jc, edc);

    // weights + init state
    wconv_kernel<<<(WTOT + 255) / 256, 256, 0, stream>>>(msg_W1, msg_W2, upd_U, upd_V,
                                                         upd_Ws1, upd_Ws2, ro_W1, ro_W2,
                                                         fc_W1, fc_W2, wt_h, wt_l);
    hipMemsetAsync(vA, 0, (size_t)3 * NF * 4, stream);
    embed_kernel<<<(NA * F + 255) / 256, 256, 0, stream>>>(z, embed, s, sh_, sl_);

    const int GX = (NA + 127) / 128;  // 157
    const int EW = (NA * F + 255) / 256;
    for (int l = 0; l < 3; l++) {
        const __bf16* w1h = wt_h + (size_t)l * WSEG,          *w1l = wt_l + (size_t)l * WSEG;
        const __bf16* w2h = w1h + 16384,  *w2l = w1l + 16384;
        const __bf16* uh  = w1h + 65536,  *ul  = w1l + 65536;
        const __bf16* vh  = w1h + 81920,  *vl  = w1l + 81920;
        const __bf16* s1h = w1h + 98304,  *s1l = w1l + 98304;
        const __bf16* s2h = w1h + 131072, *s2l = w1l + 131072;

        mgemm_kernel<1, 1><<<dim3(GX, 1), 512, 0, stream>>>(sh_, sl_, w1h, w1l,
            msg_b1 + (size_t)l * 128, 128, 128, nullptr, hid_h, hid_l);
        mgemm_kernel<0, 0><<<dim3(GX, 3), 512, 0, stream>>>(hid_h, hid_l, w2h, w2l,
            msg_b2 + (size_t)l * 384, 128, 384, phi, nullptr, nullptr);
        msg_kernel<<<4096, 128, 0, stream>>>(phi, edc, jc, offs,
            msg_Wd + (size_t)l * 20 * 384, msg_bd + (size_t)l * 384,
            vA, s, sh_, sl_, vBh, vBl, mcur + l);
        mgemm_uvvv_kernel<<<dim3(GX, 1, 6), 512, 0, stream>>>(vBh, vBl, uh, ul, vh, vl, uv, vv);
        mgemm_ws1_kernel<<<dim3(GX, 1), 512, 0, stream>>>(sh_, sl_, vv, s1h, s1l,
            upd_bs1 + (size_t)l * 128, hid_h, hid_l);
        mgemm_kernel<0, 0><<<dim3(GX, 3), 512, 0, stream>>>(hid_h, hid_l, s2h, s2l,
            upd_bs2 + (size_t)l * 384, 128, 384, phi, nullptr, nullptr);
        update_kernel<<<EW, 256, 0, stream>>>(phi, uv, vv, vBh, vBl, vA, s, sh_, sl_);
    }

    // readout (split-bf16 mgemm)
    const __bf16* roh = wt_h + WRO, *rol = wt_l + WRO;
    mgemm_kernel<1, 1><<<dim3(GX, 1), 512, 0, stream>>>(sh_, sl_, roh, rol,
        ro_b1, 128, 64, nullptr, t1h, t1l);
    mgemm_kernel<0, 1><<<dim3(GX, 1), 512, 0, stream>>>(t1h, t1l, roh + 8192, rol + 8192,
        ro_b2, 64, 64, nullptr, t2h, t2l);
    mgemm_kernel<2, 1><<<dim3(GX, 1), 512, 0, stream>>>(t2h, t2l, roh + 12288, rol + 12288,
        fc_b1, 64, 128, nullptr, t3h, t3l);
    mgemm_kernel<2, 0><<<dim3(GX, 1), 512, 0, stream>>>(t3h, t3l, roh + 20480, rol + 20480,
        fc_b2, 128, 128, t4, nullptr, nullptr);
    head_kernel<<<NA / 4, 256, 0, stream>>>(t4, fc_Wo, fc_bo, out);
}

// Round 11
// 601.161 us; speedup vs baseline: 2.1605x; 2.1605x over previous
//
#include <hip/hip_runtime.h>
#include <math.h>

static const int NA = 20000;
static const int NE = 320000;
static const int F  = 128;
static const long NF = (long)NA * F;   // 2,560,000

typedef short short8 __attribute__((ext_vector_type(8)));   // 8 bf16 (4 VGPRs)
typedef float f32x4  __attribute__((ext_vector_type(4)));

// ---------------------------------------------------------------- geometry (+ fused hist)
__global__ void geom_kernel(const float* __restrict__ xyz, const int* __restrict__ nbrs,
                            float* __restrict__ edata, int* __restrict__ act,
                            int* __restrict__ cnt) {
    int e = blockIdx.x * 256 + threadIdx.x;
    if (e >= NE) return;
    int i = nbrs[2 * e], j = nbrs[2 * e + 1];
    float xi = xyz[3 * i], yi = xyz[3 * i + 1], zi = xyz[3 * i + 2];
    float xj = xyz[3 * j], yj = xyz[3 * j + 1], zj = xyz[3 * j + 2];
    float rx = xj - xi, ry = yj - yi, rz = zj - zi;
    float d2 = rx * rx + ry * ry + rz * rz + 1e-15f;
    float d = sqrtf(d2);
    if (d >= 5.0f) { act[e] = 0; return; }
    act[e] = 1;
    atomicAdd(&cnt[i], 1);
    float inv = 1.0f / d;
    float fc = 0.5f * (cosf(d * (float)M_PI / 5.0f) + 1.0f);
    float* ed = edata + (size_t)e * 24;
    ed[0] = fc; ed[1] = rx * inv; ed[2] = ry * inv; ed[3] = rz * inv;
    float x = d * (float)M_PI / 5.0f;
    float s1 = sinf(x), c1 = cosf(x);
    float skm1 = 0.f, sk = s1;
    float twoc = 2.f * c1;
    float scale = inv * fc;
    #pragma unroll
    for (int k = 0; k < 20; k++) {
        ed[4 + k] = sk * scale;
        float skp1 = twoc * sk - skm1;
        skm1 = sk; sk = skp1;
    }
}

// ---------------------------------------------------------------- CSR build (active edges only)
__global__ __launch_bounds__(1024) void scan_kernel(const int* __restrict__ cnt, int* __restrict__ offs) {
    __shared__ int sh[1024];
    const int CH = 20;
    int t = threadIdx.x;
    int base = t * CH;
    int c[CH];
    int tot = 0;
    #pragma unroll
    for (int k = 0; k < CH; k++) {
        int idx = base + k;
        c[k] = (idx < NA) ? cnt[idx] : 0;
        tot += c[k];
    }
    sh[t] = tot;
    __syncthreads();
    for (int o = 1; o < 1024; o <<= 1) {
        int v = (t >= o) ? sh[t - o] : 0;
        __syncthreads();
        sh[t] += v;
        __syncthreads();
    }
    int run = sh[t] - tot;
    #pragma unroll
    for (int k = 0; k < CH; k++) {
        int idx = base + k;
        if (idx < NA) offs[idx] = run;
        run += c[k];
    }
    if (t == 1023) offs[NA] = sh[1023];
}

__global__ void fill_kernel(const int* __restrict__ nbrs, const int* __restrict__ act,
                            const int* __restrict__ offs, int* __restrict__ cur,
                            const float* __restrict__ edata,
                            int* __restrict__ jc, float* __restrict__ edc) {
    int e = blockIdx.x * 256 + threadIdx.x;
    if (e >= NE || !act[e]) return;
    int i = nbrs[2 * e];
    int q = offs[i] + atomicAdd(&cur[i], 1);
    jc[q] = nbrs[2 * e + 1];
    const float4* src = (const float4*)(edata + (size_t)e * 24);
    float4* dst = (float4*)(edc + (size_t)q * 24);
    #pragma unroll
    for (int k = 0; k < 6; k++) dst[k] = src[k];
}

// ---------------------------------------------------------------- embed (+ split)
__global__ void embed_kernel(const int* __restrict__ z, const float* __restrict__ embed,
                             float* __restrict__ s, __bf16* __restrict__ sh_, __bf16* __restrict__ sl_) {
    int idx = blockIdx.x * 256 + threadIdx.x;
    if (idx >= NA * F) return;
    int n = idx >> 7, f = idx & 127;
    float v = embed[z[n] * F + f];
    s[idx] = v;
    __bf16 h = (__bf16)v;
    sh_[idx] = h; sl_[idx] = (__bf16)(v - (float)h);
}

// ---------------------------------------------------------------- weight transpose + split
static const int WSEG = 180224;
static const int WRO  = 3 * WSEG;        // 540672
static const int WTOT = WRO + 36864;     // 577536

__global__ void wconv_kernel(const float* __restrict__ W1, const float* __restrict__ W2,
                             const float* __restrict__ U, const float* __restrict__ V,
                             const float* __restrict__ Ws1, const float* __restrict__ Ws2,
                             const float* __restrict__ roW1, const float* __restrict__ roW2,
                             const float* __restrict__ fcW1, const float* __restrict__ fcW2,
                             __bf16* __restrict__ wh, __bf16* __restrict__ wl) {
    int g = blockIdx.x * 256 + threadIdx.x;
    if (g >= WTOT) return;
    const float* src; int K, N, idx;
    if (g < WRO) {
        int lay = g / WSEG, o = g - lay * WSEG;
        if (o < 16384)       { src = W1  + (size_t)lay * 16384; K = 128; N = 128; idx = o; }
        else if (o < 65536)  { src = W2  + (size_t)lay * 49152; K = 128; N = 384; idx = o - 16384; }
        else if (o < 81920)  { src = U   + (size_t)lay * 16384; K = 128; N = 128; idx = o - 65536; }
        else if (o < 98304)  { src = V   + (size_t)lay * 16384; K = 128; N = 128; idx = o - 81920; }
        else if (o < 131072) { src = Ws1 + (size_t)lay * 32768; K = 256; N = 128; idx = o - 98304; }
        else                 { src = Ws2 + (size_t)lay * 49152; K = 128; N = 384; idx = o - 131072; }
    } else {
        int o2 = g - WRO;
        if (o2 < 8192)       { src = roW1; K = 128; N = 64;  idx = o2; }
        else if (o2 < 12288) { src = roW2; K = 64;  N = 64;  idx = o2 - 8192; }
        else if (o2 < 20480) { src = fcW1; K = 64;  N = 128; idx = o2 - 12288; }
        else                 { src = fcW2; K = 128; N = 128; idx = o2 - 20480; }
    }
    int n = idx / K, k = idx - n * K;
    float v = src[(size_t)k * N + n];
    __bf16 h = (__bf16)v;
    wh[g] = h; wl[g] = (__bf16)(v - (float)h);
}

// ---------------------------------------------------------------- split-bf16 MFMA GEMM
// 128x128 tile, BK=64, 512 threads / 8 waves (2 row-halves x 4 col-quarters),
// 16x16x32 MFMA, 3 products (hh, hl, lh). Per-wave sub-tile 64x32 (acc 4x2).
// LDS: 4 comps x [128][64] bf16 = 64KB -> 2 blocks/CU = 16 waves/CU.
// Write-side XOR swizzle slot^=row&7, same involution on read.
template<int ACT, int MODE>   // ACT: 0 none, 1 silu, 2 relu. MODE: 0 f32 out, 1 split bf16 out
__device__ __forceinline__ void mgemm_body(char* ldsb,
    const __bf16* __restrict__ Ah, const __bf16* __restrict__ Al,
    const __bf16* __restrict__ Bh, const __bf16* __restrict__ Bl,
    const float* __restrict__ bias, int K, int N, int c0,
    float* __restrict__ Cf, __bf16* __restrict__ Ch, __bf16* __restrict__ Cl) {
    int tid = threadIdx.x;
    int w = tid >> 6, l = tid & 63;
    int r0 = blockIdx.x * 128;

    int srow = tid >> 3, sl = tid & 7;            // srow in [0,64)

    int wr = w >> 2, wc = w & 3;                  // 2 x 4 wave grid
    int lrow = l & 15, lk = l >> 4;
    uint32_t arow[4], axor[4], brow[2], bxor[2];
    #pragma unroll
    for (int m = 0; m < 4; m++) {
        int row = wr * 64 + m * 16 + lrow;
        arow[m] = (uint32_t)row * 128u; axor[m] = (uint32_t)((row & 7) << 4);
    }
    #pragma unroll
    for (int n = 0; n < 2; n++) {
        int row = wc * 32 + n * 16 + lrow;
        brow[n] = (uint32_t)row * 128u; bxor[n] = (uint32_t)((row & 7) << 4);
    }

    f32x4 acc[4][2];
    #pragma unroll
    for (int m = 0; m < 4; m++)
        #pragma unroll
        for (int n = 0; n < 2; n++) acc[m][n] = (f32x4){0.f, 0.f, 0.f, 0.f};

    const char* pAh = (const char*)Ah;
    const char* pAl = (const char*)Al;
    const char* pBh = (const char*)Bh;
    const char* pBl = (const char*)Bl;

    for (int k0 = 0; k0 < K; k0 += 64) {
        #pragma unroll
        for (int t = 0; t < 2; t++) {
            int row = srow + t * 64;
            uint32_t dst = (uint32_t)row * 128u + (uint32_t)(((sl ^ (row & 7)) << 4));
            int ga = min(r0 + row, NA - 1);
            int gb = min(c0 + row, N - 1);
            size_t soA = ((size_t)ga * K + k0 + sl * 8) * 2;
            size_t soB = ((size_t)gb * K + k0 + sl * 8) * 2;
            *(float4*)(ldsb + dst)         = *(const float4*)(pAh + soA);
            *(float4*)(ldsb + 16384 + dst) = *(const float4*)(pAl + soA);
            *(float4*)(ldsb + 32768 + dst) = *(const float4*)(pBh + soB);
            *(float4*)(ldsb + 49152 + dst) = *(const float4*)(pBl + soB);
        }
        __syncthreads();
        #pragma unroll
        for (int kh = 0; kh < 2; kh++) {
            uint32_t ks = (uint32_t)((kh * 4 + lk) * 16);
            short8 fah[4], fal[4], fbh[2], fbl[2];
            #pragma unroll
            for (int m = 0; m < 4; m++) {
                uint32_t ob = arow[m] + (ks ^ axor[m]);
                fah[m] = *(const short8*)(ldsb + ob);
                fal[m] = *(const short8*)(ldsb + 16384 + ob);
            }
            #pragma unroll
            for (int n = 0; n < 2; n++) {
                uint32_t ob = brow[n] + (ks ^ bxor[n]);
                fbh[n] = *(const short8*)(ldsb + 32768 + ob);
                fbl[n] = *(const short8*)(ldsb + 49152 + ob);
            }
            #pragma unroll
            for (int m = 0; m < 4; m++)
                #pragma unroll
                for (int n = 0; n < 2; n++) {
                    acc[m][n] = __builtin_amdgcn_mfma_f32_16x16x32_bf16(fah[m], fbh[n], acc[m][n], 0, 0, 0);
                    acc[m][n] = __builtin_amdgcn_mfma_f32_16x16x32_bf16(fah[m], fbl[n], acc[m][n], 0, 0, 0);
                    acc[m][n] = __builtin_amdgcn_mfma_f32_16x16x32_bf16(fal[m], fbh[n], acc[m][n], 0, 0, 0);
                }
        }
        __syncthreads();
    }

    // epilogue: C col = lane&15, row = (lane>>4)*4 + reg (m89-verified)
    #pragma unroll
    for (int n = 0; n < 2; n++) {
        int gc = c0 + wc * 32 + n * 16 + lrow;
        float bb = (bias && gc < N) ? bias[gc] : 0.f;
        #pragma unroll
        for (int m = 0; m < 4; m++) {
            #pragma unroll
            for (int r = 0; r < 4; r++) {
                int gr = r0 + wr * 64 + m * 16 + lk * 4 + r;
                if (gr < NA && gc < N) {
                    float y = acc[m][n][r] + bb;
                    if (ACT == 1) y = y / (1.f + expf(-y));
                    if (ACT == 2) y = fmaxf(y, 0.f);
                    if (MODE == 0) {
                        Cf[(size_t)gr * N + gc] = y;
                    } else {
                        __bf16 h = (__bf16)y;
                        Ch[(size_t)gr * N + gc] = h;
                        Cl[(size_t)gr * N + gc] = (__bf16)(y - (float)h);
                    }
                }
            }
        }
    }
}

template<int ACT, int MODE>
__global__ __launch_bounds__(512, 4) void mgemm_kernel(
    const __bf16* __restrict__ Ah, const __bf16* __restrict__ Al,
    const __bf16* __restrict__ Bh, const __bf16* __restrict__ Bl,
    const float* __restrict__ bias, int K, int N,
    float* __restrict__ Cf, __bf16* __restrict__ Ch, __bf16* __restrict__ Cl) {
    __shared__ __attribute__((aligned(16))) char lds[65536];
    mgemm_body<ACT, MODE>(lds, Ah, Al, Bh, Bl, bias, K, N, blockIdx.y * 128, Cf, Ch, Cl);
}

// u_v / v_v batched: grid.z = 6 -> (mat = z/3 in {U,V}, d = z%3); fp32 out
__global__ __launch_bounds__(512, 4) void mgemm_uvvv_kernel(
    const __bf16* __restrict__ vBh, const __bf16* __restrict__ vBl,
    const __bf16* __restrict__ Uth, const __bf16* __restrict__ Utl,
    const __bf16* __restrict__ Vth, const __bf16* __restrict__ Vtl,
    float* __restrict__ uv, float* __restrict__ vv) {
    __shared__ __attribute__((aligned(16))) char lds[65536];
    int zz = blockIdx.z, d = zz % 3;
    const __bf16* Ah = vBh + (size_t)d * NF;
    const __bf16* Al = vBl + (size_t)d * NF;
    const __bf16* Bh = (zz < 3) ? Uth : Vth;
    const __bf16* Bl = (zz < 3) ? Utl : Vtl;
    float* Cf = ((zz < 3) ? uv : vv) + (size_t)d * NF;
    mgemm_body<0, 0>(lds, Ah, Al, Bh, Bl, nullptr, 128, 128, 0, Cf, nullptr, nullptr);
}

// Ws1 GEMM with fused "stack": A cols 0-127 = s (split, POST-message), cols
// 128-255 = vnorm computed on the fly from fp32 vv. K=256, N=128, silu, split out.
__global__ __launch_bounds__(512, 4) void mgemm_ws1_kernel(
    const __bf16* __restrict__ sh_, const __bf16* __restrict__ sl_,
    const float* __restrict__ vv,
    const __bf16* __restrict__ Bh, const __bf16* __restrict__ Bl,
    const float* __restrict__ bias,
    __bf16* __restrict__ Ch, __bf16* __restrict__ Cl) {
    __shared__ __attribute__((aligned(16))) char ldsb[65536];
    const int K = 256, N = 128;
    int tid = threadIdx.x;
    int w = tid >> 6, l = tid & 63;
    int r0 = blockIdx.x * 128;
    int srow = tid >> 3, sl = tid & 7;
    int wr = w >> 2, wc = w & 3;
    int lrow = l & 15, lk = l >> 4;
    uint32_t arow[4], axor[4], brow[2], bxor[2];
    #pragma unroll
    for (int m = 0; m < 4; m++) {
        int row = wr * 64 + m * 16 + lrow;
        arow[m] = (uint32_t)row * 128u; axor[m] = (uint32_t)((row & 7) << 4);
    }
    #pragma unroll
    for (int n = 0; n < 2; n++) {
        int row = wc * 32 + n * 16 + lrow;
        brow[n] = (uint32_t)row * 128u; bxor[n] = (uint32_t)((row & 7) << 4);
    }
    f32x4 acc[4][2];
    #pragma unroll
    for (int m = 0; m < 4; m++)
        #pragma unroll
        for (int n = 0; n < 2; n++) acc[m][n] = (f32x4){0.f, 0.f, 0.f, 0.f};

    for (int k0 = 0; k0 < K; k0 += 64) {
        #pragma unroll
        for (int t = 0; t < 2; t++) {
            int row = srow + t * 64;
            uint32_t dst = (uint32_t)row * 128u + (uint32_t)(((sl ^ (row & 7)) << 4));
            int ga = min(r0 + row, NA - 1);
            int gb = row;   // N=128 weight rows
            size_t soB = ((size_t)gb * K + k0 + sl * 8) * 2;
            *(float4*)(ldsb + 32768 + dst) = *(const float4*)((const char*)Bh + soB);
            *(float4*)(ldsb + 49152 + dst) = *(const float4*)((const char*)Bl + soB);
            if (k0 < 128) {
                size_t soA = ((size_t)ga * 128 + k0 + sl * 8) * 2;
                *(float4*)(ldsb + dst)         = *(const float4*)((const char*)sh_ + soA);
                *(float4*)(ldsb + 16384 + dst) = *(const float4*)((const char*)sl_ + soA);
            } else {
                int f0 = (k0 - 128) + sl * 8;
                size_t b = (size_t)ga * 128 + f0;
                float4 a0 = *(const float4*)(vv + b);
                float4 a1 = *(const float4*)(vv + b + 4);
                float4 b0 = *(const float4*)(vv + NF + b);
                float4 b1 = *(const float4*)(vv + NF + b + 4);
                float4 c0v = *(const float4*)(vv + 2 * NF + b);
                float4 c1v = *(const float4*)(vv + 2 * NF + b + 4);
                float xs[8] = {a0.x, a0.y, a0.z, a0.w, a1.x, a1.y, a1.z, a1.w};
                float ys[8] = {b0.x, b0.y, b0.z, b0.w, b1.x, b1.y, b1.z, b1.w};
                float zs[8] = {c0v.x, c0v.y, c0v.z, c0v.w, c1v.x, c1v.y, c1v.z, c1v.w};
                union { short8 s; float4 q; } hi, lo;
                #pragma unroll
                for (int k = 0; k < 8; k++) {
                    float vn = sqrtf(xs[k] * xs[k] + ys[k] * ys[k] + zs[k] * zs[k] + 1e-15f);
                    __bf16 h = (__bf16)vn;
                    hi.s[k] = *(short*)&h;
                    __bf16 lo_b = (__bf16)(vn - (float)h);
                    lo.s[k] = *(short*)&lo_b;
                }
                *(float4*)(ldsb + dst)         = hi.q;
                *(float4*)(ldsb + 16384 + dst) = lo.q;
            }
        }
        __syncthreads();
        #pragma unroll
        for (int kh = 0; kh < 2; kh++) {
            uint32_t ks = (uint32_t)((kh * 4 + lk) * 16);
            short8 fah[4], fal[4], fbh[2], fbl[2];
            #pragma unroll
            for (int m = 0; m < 4; m++) {
                uint32_t ob = arow[m] + (ks ^ axor[m]);
                fah[m] = *(const short8*)(ldsb + ob);
                fal[m] = *(const short8*)(ldsb + 16384 + ob);
            }
            #pragma unroll
            for (int n = 0; n < 2; n++) {
                uint32_t ob = brow[n] + (ks ^ bxor[n]);
                fbh[n] = *(const short8*)(ldsb + 32768 + ob);
                fbl[n] = *(const short8*)(ldsb + 49152 + ob);
            }
            #pragma unroll
            for (int m = 0; m < 4; m++)
                #pragma unroll
                for (int n = 0; n < 2; n++) {
                    acc[m][n] = __builtin_amdgcn_mfma_f32_16x16x32_bf16(fah[m], fbh[n], acc[m][n], 0, 0, 0);
                    acc[m][n] = __builtin_amdgcn_mfma_f32_16x16x32_bf16(fah[m], fbl[n], acc[m][n], 0, 0, 0);
                    acc[m][n] = __builtin_amdgcn_mfma_f32_16x16x32_bf16(fal[m], fbh[n], acc[m][n], 0, 0, 0);
                }
        }
        __syncthreads();
    }
    #pragma unroll
    for (int n = 0; n < 2; n++) {
        int gc = wc * 32 + n * 16 + lrow;
        float bb = bias[gc];
        #pragma unroll
        for (int m = 0; m < 4; m++) {
            #pragma unroll
            for (int r = 0; r < 4; r++) {
                int gr = r0 + wr * 64 + m * 16 + lk * 4 + r;
                if (gr < NA) {
                    float y = acc[m][n][r] + bb;
                    y = y / (1.f + expf(-y));
                    __bf16 h = (__bf16)y;
                    Ch[(size_t)gr * N + gc] = h;
                    Cl[(size_t)gr * N + gc] = (__bf16)(y - (float)h);
                }
            }
        }
    }
}

// ---------------------------------------------------------------- message + aggregation
// one atom per 128-thread block (R9 structure — work-stealing regressed 5.6x);
// v state interleaved [n][3][128]; refreshes sh_/sl_ for the fused Ws1 gemm.
__global__ __launch_bounds__(128) void msg_kernel(
    const float* __restrict__ phi, const float* __restrict__ edc,
    const int* __restrict__ jc, const int* __restrict__ offs,
    const float* __restrict__ Wd, const float* __restrict__ bd,
    const float* __restrict__ vin, float* __restrict__ s,
    __bf16* __restrict__ sh_, __bf16* __restrict__ sl_,
    __bf16* __restrict__ vBh, __bf16* __restrict__ vBl) {
    int i = blockIdx.x;
    int f = threadIdx.x;
    float wd0[20], wd1[20], wd2[20];
    #pragma unroll
    for (int k = 0; k < 20; k++) {
        wd0[k] = Wd[k * 384 + f];
        wd1[k] = Wd[k * 384 + 128 + f];
        wd2[k] = Wd[k * 384 + 256 + f];
    }
    float b0 = bd[f], b1 = bd[128 + f], b2 = bd[256 + f];
    float accS = 0.f, aV0 = 0.f, aV1 = 0.f, aV2 = 0.f;
    int p0 = offs[i], p1 = offs[i + 1];
    for (int p = p0; p < p1; ++p) {
        int j = jc[p];
        const float4* ed = (const float4*)(edc + (size_t)p * 24);
        float4 q0 = ed[0], q1 = ed[1], q2 = ed[2], q3 = ed[3], q4 = ed[4], q5 = ed[5];
        float fc = q0.x, ux = q0.y, uy = q0.z, uz = q0.w;
        float rb[20];
        rb[0]=q1.x; rb[1]=q1.y; rb[2]=q1.z; rb[3]=q1.w;
        rb[4]=q2.x; rb[5]=q2.y; rb[6]=q2.z; rb[7]=q2.w;
        rb[8]=q3.x; rb[9]=q3.y; rb[10]=q3.z; rb[11]=q3.w;
        rb[12]=q4.x; rb[13]=q4.y; rb[14]=q4.z; rb[15]=q4.w;
        rb[16]=q5.x; rb[17]=q5.y; rb[18]=q5.z; rb[19]=q5.w;
        float w0 = b0 * fc, w1 = b1 * fc, w2 = b2 * fc;
        #pragma unroll
        for (int k = 0; k < 20; k++) {
            w0 += rb[k] * wd0[k];
            w1 += rb[k] * wd1[k];
            w2 += rb[k] * wd2[k];
        }
        const float* pj = phi + (size_t)j * 384;
        float i0 = pj[f] * w0, i1 = pj[128 + f] * w1, i2 = pj[256 + f] * w2;
        const float* vj = vin + (size_t)j * 384;
        accS += i1;
        aV0 += i2 * ux + i0 * vj[f];
        aV1 += i2 * uy + i0 * vj[128 + f];
        aV2 += i2 * uz + i0 * vj[256 + f];
    }
    size_t ib = (size_t)i * F + f;
    float ns = s[ib] + accS;
    s[ib] = ns;
    __bf16 hs = (__bf16)ns;
    sh_[ib] = hs; sl_[ib] = (__bf16)(ns - (float)hs);
    const float* vi = vin + (size_t)i * 384;
    float o0 = vi[f] + aV0;
    float o1 = vi[128 + f] + aV1;
    float o2 = vi[256 + f] + aV2;
    __bf16 h0 = (__bf16)o0, h1 = (__bf16)o1, h2 = (__bf16)o2;
    vBh[ib] = h0;            vBl[ib] = (__bf16)(o0 - (float)h0);
    vBh[NF + ib] = h1;       vBl[NF + ib] = (__bf16)(o1 - (float)h1);
    vBh[2 * NF + ib] = h2;   vBl[2 * NF + ib] = (__bf16)(o2 - (float)h2);
}

// ---------------------------------------------------------------- update
__global__ void update_kernel(const float* __restrict__ spl, const float* __restrict__ uv,
                              const float* __restrict__ vv,
                              const __bf16* __restrict__ vBh, const __bf16* __restrict__ vBl,
                              float* __restrict__ vout, float* __restrict__ s,
                              __bf16* __restrict__ sh_, __bf16* __restrict__ sl_) {
    int idx = blockIdx.x * 256 + threadIdx.x;
    if (idx >= NA * F) return;
    int n = idx >> 7, f = idx & 127;
    const float* sp = spl + (size_t)n * 384;
    float avv = sp[f], asv = sp[128 + f], ass = sp[256 + f];
    float dot = 0.f;
    #pragma unroll
    for (int d = 0; d < 3; d++) {
        float u = uv[d * NF + idx];
        float vb = (float)vBh[d * NF + idx] + (float)vBl[d * NF + idx];
        vout[(size_t)n * 384 + d * 128 + f] = vb + u * avv;
        dot += u * vv[d * NF + idx];
    }
    float ns = s[idx] + dot * asv + ass;
    s[idx] = ns;
    __bf16 h = (__bf16)ns;
    sh_[idx] = h; sl_[idx] = (__bf16)(ns - (float)h);
}

// ---------------------------------------------------------------- head
__global__ __launch_bounds__(256) void head_kernel(const float* __restrict__ h,
                                                   const float* __restrict__ Wo,
                                                   const float* __restrict__ bo,
                                                   float* __restrict__ out) {
    int n = blockIdx.x * 4 + (threadIdx.x >> 6);
    int lane = threadIdx.x & 63;
    if (n >= NA) return;
    float p = h[(size_t)n * 128 + lane] * Wo[lane] + h[(size_t)n * 128 + 64 + lane] * Wo[64 + lane];
    #pragma unroll
    for (int o = 32; o > 0; o >>= 1) p += __shfl_down(p, o);
    if (lane == 0) out[n] = p + bo[0];
}

// ---------------------------------------------------------------- host
extern "C" void kernel_launch(void* const* d_in, const int* in_sizes, int n_in,
                              void* d_out, int out_size, void* d_ws, size_t ws_size,
                              hipStream_t stream) {
    const float* xyz    = (const float*)d_in[0];
    const int*   z      = (const int*)d_in[1];
    const int*   nbrs   = (const int*)d_in[2];
    const float* embed  = (const float*)d_in[3];
    const float* msg_W1 = (const float*)d_in[4];
    const float* msg_b1 = (const float*)d_in[5];
    const float* msg_W2 = (const float*)d_in[6];
    const float* msg_b2 = (const float*)d_in[7];
    const float* msg_Wd = (const float*)d_in[8];
    const float* msg_bd = (const float*)d_in[9];
    const float* upd_U  = (const float*)d_in[10];
    const float* upd_V  = (const float*)d_in[11];
    const float* upd_Ws1= (const float*)d_in[12];
    const float* upd_bs1= (const float*)d_in[13];
    const float* upd_Ws2= (const float*)d_in[14];
    const float* upd_bs2= (const float*)d_in[15];
    const float* ro_W1  = (const float*)d_in[16];
    const float* ro_b1  = (const float*)d_in[17];
    const float* ro_W2  = (const float*)d_in[18];
    const float* ro_b2  = (const float*)d_in[19];
    const float* fc_W1  = (const float*)d_in[20];
    const float* fc_b1  = (const float*)d_in[21];
    const float* fc_W2  = (const float*)d_in[22];
    const float* fc_b2  = (const float*)d_in[23];
    const float* fc_Wo  = (const float*)d_in[24];
    const float* fc_bo  = (const float*)d_in[25];
    float* out = (float*)d_out;

    char* ws = (char*)d_ws;
    size_t off = 0;
    auto alloc = [&](size_t nbytes) -> char* {
        char* p = ws + off;
        off += (nbytes + 255) / 256 * 256;
        return p;
    };
    // total ~240.6 MB (R5/R7/R9 passed at this size; 271 faulted)
    float*  edc   = (float*)alloc((size_t)NE * 24 * 4);
    float*  s     = (float*)alloc((size_t)NA * F * 4);
    __bf16* sh_   = (__bf16*)alloc((size_t)NA * F * 2);
    __bf16* sl_   = (__bf16*)alloc((size_t)NA * F * 2);
    float*  vA    = (float*)alloc((size_t)3 * NF * 4);     // interleaved [n][3][128]
    __bf16* vBh   = (__bf16*)alloc((size_t)3 * NF * 2);
    __bf16* vBl   = (__bf16*)alloc((size_t)3 * NF * 2);
    float*  phi   = (float*)alloc((size_t)NA * 384 * 4);   // also spl + readout t4
    __bf16* hid_h = (__bf16*)alloc((size_t)NA * F * 2);    // also t1h
    __bf16* hid_l = (__bf16*)alloc((size_t)NA * F * 2);    // also t1l
    float*  uv    = (float*)alloc((size_t)3 * NF * 4);     // also geometry temp
    float*  vv    = (float*)alloc((size_t)3 * NF * 4);
    __bf16* stkh  = (__bf16*)alloc((size_t)NA * 256 * 2);  // readout t2h
    __bf16* stkl  = (__bf16*)alloc((size_t)NA * 256 * 2);  // readout t2l
    __bf16* wt_h  = (__bf16*)alloc((size_t)WTOT * 2);
    __bf16* wt_l  = (__bf16*)alloc((size_t)WTOT * 2);
    int* act  = (int*)alloc((size_t)NE * 4);
    int* cnt2 = (int*)alloc((size_t)2 * NA * 4);           // cnt | cur, one memset
    int* offs = (int*)alloc((size_t)(NA + 1) * 4);
    int* jc   = (int*)alloc((size_t)NE * 4);
    int* cnt = cnt2;
    int* cur = cnt2 + NA;

    float* edata = uv;                 // geometry temp (dead before uv first written)
    __bf16* t1h = hid_h, *t1l = hid_l; // readout temps (dead after layers)
    __bf16* t2h = stkh,  *t2l = stkl;
    __bf16* t3h = sh_,   *t3l = sl_;   // sh_ dead after readout gemm1 reads it
    float*  t4  = phi;

    // geometry + active-edge CSR
    hipMemsetAsync(cnt2, 0, (size_t)2 * NA * 4, stream);
    geom_kernel<<<(NE + 255) / 256, 256, 0, stream>>>(xyz, nbrs, edata, act, cnt);
    scan_kernel<<<1, 1024, 0, stream>>>(cnt, offs);
    fill_kernel<<<(NE + 255) / 256, 256, 0, stream>>>(nbrs, act, offs, cur, edata, jc, edc);

    // weights + init state
    wconv_kernel<<<(WTOT + 255) / 256, 256, 0, stream>>>(msg_W1, msg_W2, upd_U, upd_V,
                                                         upd_Ws1, upd_Ws2, ro_W1, ro_W2,
                                                         fc_W1, fc_W2, wt_h, wt_l);
    hipMemsetAsync(vA, 0, (size_t)3 * NF * 4, stream);
    embed_kernel<<<(NA * F + 255) / 256, 256, 0, stream>>>(z, embed, s, sh_, sl_);

    const int GX = (NA + 127) / 128;  // 157
    const int EW = (NA * F + 255) / 256;
    for (int l = 0; l < 3; l++) {
        const __bf16* w1h = wt_h + (size_t)l * WSEG,          *w1l = wt_l + (size_t)l * WSEG;
        const __bf16* w2h = w1h + 16384,  *w2l = w1l + 16384;
        const __bf16* uh  = w1h + 65536,  *ul  = w1l + 65536;
        const __bf16* vh  = w1h + 81920,  *vl  = w1l + 81920;
        const __bf16* s1h = w1h + 98304,  *s1l = w1l + 98304;
        const __bf16* s2h = w1h + 131072, *s2l = w1l + 131072;

        mgemm_kernel<1, 1><<<dim3(GX, 1), 512, 0, stream>>>(sh_, sl_, w1h, w1l,
            msg_b1 + (size_t)l * 128, 128, 128, nullptr, hid_h, hid_l);
        mgemm_kernel<0, 0><<<dim3(GX, 3), 512, 0, stream>>>(hid_h, hid_l, w2h, w2l,
            msg_b2 + (size_t)l * 384, 128, 384, phi, nullptr, nullptr);
        msg_kernel<<<NA, 128, 0, stream>>>(phi, edc, jc, offs,
            msg_Wd + (size_t)l * 20 * 384, msg_bd + (size_t)l * 384,
            vA, s, sh_, sl_, vBh, vBl);
        mgemm_uvvv_kernel<<<dim3(GX, 1, 6), 512, 0, stream>>>(vBh, vBl, uh, ul, vh, vl, uv, vv);
        mgemm_ws1_kernel<<<dim3(GX, 1), 512, 0, stream>>>(sh_, sl_, vv, s1h, s1l,
            upd_bs1 + (size_t)l * 128, hid_h, hid_l);
        mgemm_kernel<0, 0><<<dim3(GX, 3), 512, 0, stream>>>(hid_h, hid_l, s2h, s2l,
            upd_bs2 + (size_t)l * 384, 128, 384, phi, nullptr, nullptr);
        update_kernel<<<EW, 256, 0, stream>>>(phi, uv, vv, vBh, vBl, vA, s, sh_, sl_);
    }

    // readout (split-bf16 mgemm)
    const __bf16* roh = wt_h + WRO, *rol = wt_l + WRO;
    mgemm_kernel<1, 1><<<dim3(GX, 1), 512, 0, stream>>>(sh_, sl_, roh, rol,
        ro_b1, 128, 64, nullptr, t1h, t1l);
    mgemm_kernel<0, 1><<<dim3(GX, 1), 512, 0, stream>>>(t1h, t1l, roh + 8192, rol + 8192,
        ro_b2, 64, 64, nullptr, t2h, t2l);
    mgemm_kernel<2, 1><<<dim3(GX, 1), 512, 0, stream>>>(t2h, t2l, roh + 12288, rol + 12288,
        fc_b1, 64, 128, nullptr, t3h, t3l);
    mgemm_kernel<2, 0><<<dim3(GX, 1), 512, 0, stream>>>(t3h, t3l, roh + 20480, rol + 20480,
        fc_b2, 128, 128, t4, nullptr, nullptr);
    head_kernel<<<NA / 4, 256, 0, stream>>>(t4, fc_Wo, fc_bo, out);
}

// Round 13
// 578.373 us; speedup vs baseline: 2.2457x; 1.0394x over previous
//
#include <hip/hip_runtime.h>
#include <math.h>

static const int NA = 20000;
static const int NE = 320000;
static const int F  = 128;
static const long NF = (long)NA * F;   // 2,560,000

typedef short short8 __attribute__((ext_vector_type(8)));   // 8 bf16 raw bits (4 VGPRs)
typedef __bf16 bf16x8 __attribute__((ext_vector_type(8)));
typedef float f32x4  __attribute__((ext_vector_type(4)));

// ---------------------------------------------------------------- geometry (+ fused hist)
__global__ void geom_kernel(const float* __restrict__ xyz, const int* __restrict__ nbrs,
                            float* __restrict__ edata, int* __restrict__ act,
                            int* __restrict__ cnt) {
    int e = blockIdx.x * 256 + threadIdx.x;
    if (e >= NE) return;
    int i = nbrs[2 * e], j = nbrs[2 * e + 1];
    float xi = xyz[3 * i], yi = xyz[3 * i + 1], zi = xyz[3 * i + 2];
    float xj = xyz[3 * j], yj = xyz[3 * j + 1], zj = xyz[3 * j + 2];
    float rx = xj - xi, ry = yj - yi, rz = zj - zi;
    float d2 = rx * rx + ry * ry + rz * rz + 1e-15f;
    float d = sqrtf(d2);
    if (d >= 5.0f) { act[e] = 0; return; }
    act[e] = 1;
    atomicAdd(&cnt[i], 1);
    float inv = 1.0f / d;
    float fc = 0.5f * (cosf(d * (float)M_PI / 5.0f) + 1.0f);
    float* ed = edata + (size_t)e * 24;
    ed[0] = fc; ed[1] = rx * inv; ed[2] = ry * inv; ed[3] = rz * inv;
    float x = d * (float)M_PI / 5.0f;
    float s1 = sinf(x), c1 = cosf(x);
    float skm1 = 0.f, sk = s1;
    float twoc = 2.f * c1;
    float scale = inv * fc;
    #pragma unroll
    for (int k = 0; k < 20; k++) {
        ed[4 + k] = sk * scale;
        float skp1 = twoc * sk - skm1;
        skm1 = sk; sk = skp1;
    }
}

// ---------------------------------------------------------------- CSR build (active edges only)
__global__ __launch_bounds__(1024) void scan_kernel(const int* __restrict__ cnt, int* __restrict__ offs) {
    __shared__ int sh[1024];
    const int CH = 20;
    int t = threadIdx.x;
    int base = t * CH;
    int c[CH];
    int tot = 0;
    #pragma unroll
    for (int k = 0; k < CH; k++) {
        int idx = base + k;
        c[k] = (idx < NA) ? cnt[idx] : 0;
        tot += c[k];
    }
    sh[t] = tot;
    __syncthreads();
    for (int o = 1; o < 1024; o <<= 1) {
        int v = (t >= o) ? sh[t - o] : 0;
        __syncthreads();
        sh[t] += v;
        __syncthreads();
    }
    int run = sh[t] - tot;
    #pragma unroll
    for (int k = 0; k < CH; k++) {
        int idx = base + k;
        if (idx < NA) offs[idx] = run;
        run += c[k];
    }
    if (t == 1023) offs[NA] = sh[1023];
}

__global__ void fill_kernel(const int* __restrict__ nbrs, const int* __restrict__ act,
                            const int* __restrict__ offs, int* __restrict__ cur,
                            const float* __restrict__ edata,
                            int* __restrict__ jc, float* __restrict__ edc) {
    int e = blockIdx.x * 256 + threadIdx.x;
    if (e >= NE || !act[e]) return;
    int i = nbrs[2 * e];
    int q = offs[i] + atomicAdd(&cur[i], 1);
    jc[q] = nbrs[2 * e + 1];
    const float4* src = (const float4*)(edata + (size_t)e * 24);
    float4* dst = (float4*)(edc + (size_t)q * 24);
    #pragma unroll
    for (int k = 0; k < 6; k++) dst[k] = src[k];
}

// ---------------------------------------------------------------- embed (+ split)
__global__ void embed_kernel(const int* __restrict__ z, const float* __restrict__ embed,
                             float* __restrict__ s, __bf16* __restrict__ sh_, __bf16* __restrict__ sl_) {
    int idx = blockIdx.x * 256 + threadIdx.x;
    if (idx >= NA * F) return;
    int n = idx >> 7, f = idx & 127;
    float v = embed[z[n] * F + f];
    s[idx] = v;
    __bf16 h = (__bf16)v;
    sh_[idx] = h; sl_[idx] = (__bf16)(v - (float)h);
}

// ---------------------------------------------------------------- weight transpose + split
static const int WSEG = 180224;
static const int WRO  = 3 * WSEG;        // 540672
static const int WTOT = WRO + 36864;     // 577536

__global__ void wconv_kernel(const float* __restrict__ W1, const float* __restrict__ W2,
                             const float* __restrict__ U, const float* __restrict__ V,
                             const float* __restrict__ Ws1, const float* __restrict__ Ws2,
                             const float* __restrict__ roW1, const float* __restrict__ roW2,
                             const float* __restrict__ fcW1, const float* __restrict__ fcW2,
                             __bf16* __restrict__ wh, __bf16* __restrict__ wl) {
    int g = blockIdx.x * 256 + threadIdx.x;
    if (g >= WTOT) return;
    const float* src; int K, N, idx;
    if (g < WRO) {
        int lay = g / WSEG, o = g - lay * WSEG;
        if (o < 16384)       { src = W1  + (size_t)lay * 16384; K = 128; N = 128; idx = o; }
        else if (o < 65536)  { src = W2  + (size_t)lay * 49152; K = 128; N = 384; idx = o - 16384; }
        else if (o < 81920)  { src = U   + (size_t)lay * 16384; K = 128; N = 128; idx = o - 65536; }
        else if (o < 98304)  { src = V   + (size_t)lay * 16384; K = 128; N = 128; idx = o - 81920; }
        else if (o < 131072) { src = Ws1 + (size_t)lay * 32768; K = 256; N = 128; idx = o - 98304; }
        else                 { src = Ws2 + (size_t)lay * 49152; K = 128; N = 384; idx = o - 131072; }
    } else {
        int o2 = g - WRO;
        if (o2 < 8192)       { src = roW1; K = 128; N = 64;  idx = o2; }
        else if (o2 < 12288) { src = roW2; K = 64;  N = 64;  idx = o2 - 8192; }
        else if (o2 < 20480) { src = fcW1; K = 64;  N = 128; idx = o2 - 12288; }
        else                 { src = fcW2; K = 128; N = 128; idx = o2 - 20480; }
    }
    int n = idx / K, k = idx - n * K;
    float v = src[(size_t)k * N + n];
    __bf16 h = (__bf16)v;
    wh[g] = h; wl[g] = (__bf16)(v - (float)h);
}

// ---------------------------------------------------------------- split-bf16 MFMA GEMM
// 128x128 tile, BK=64, 512 threads / 8 waves (2x4), 16x16x32 MFMA, 3 products.
// LDS 64KB, XOR swizzle slot^=row&7 both sides.
template<int ACT, int MODE>   // ACT: 0 none, 1 silu, 2 relu. MODE: 0 f32 out, 1 split bf16 out
__device__ __forceinline__ void mgemm_body(char* ldsb,
    const __bf16* __restrict__ Ah, const __bf16* __restrict__ Al,
    const __bf16* __restrict__ Bh, const __bf16* __restrict__ Bl,
    const float* __restrict__ bias, int K, int N, int c0,
    float* __restrict__ Cf, __bf16* __restrict__ Ch, __bf16* __restrict__ Cl) {
    int tid = threadIdx.x;
    int w = tid >> 6, l = tid & 63;
    int r0 = blockIdx.x * 128;

    int srow = tid >> 3, sl = tid & 7;            // srow in [0,64)

    int wr = w >> 2, wc = w & 3;                  // 2 x 4 wave grid
    int lrow = l & 15, lk = l >> 4;
    uint32_t arow[4], axor[4], brow[2], bxor[2];
    #pragma unroll
    for (int m = 0; m < 4; m++) {
        int row = wr * 64 + m * 16 + lrow;
        arow[m] = (uint32_t)row * 128u; axor[m] = (uint32_t)((row & 7) << 4);
    }
    #pragma unroll
    for (int n = 0; n < 2; n++) {
        int row = wc * 32 + n * 16 + lrow;
        brow[n] = (uint32_t)row * 128u; bxor[n] = (uint32_t)((row & 7) << 4);
    }

    f32x4 acc[4][2];
    #pragma unroll
    for (int m = 0; m < 4; m++)
        #pragma unroll
        for (int n = 0; n < 2; n++) acc[m][n] = (f32x4){0.f, 0.f, 0.f, 0.f};

    const char* pAh = (const char*)Ah;
    const char* pAl = (const char*)Al;
    const char* pBh = (const char*)Bh;
    const char* pBl = (const char*)Bl;

    for (int k0 = 0; k0 < K; k0 += 64) {
        #pragma unroll
        for (int t = 0; t < 2; t++) {
            int row = srow + t * 64;
            uint32_t dst = (uint32_t)row * 128u + (uint32_t)(((sl ^ (row & 7)) << 4));
            int ga = min(r0 + row, NA - 1);
            int gb = min(c0 + row, N - 1);
            size_t soA = ((size_t)ga * K + k0 + sl * 8) * 2;
            size_t soB = ((size_t)gb * K + k0 + sl * 8) * 2;
            *(float4*)(ldsb + dst)         = *(const float4*)(pAh + soA);
            *(float4*)(ldsb + 16384 + dst) = *(const float4*)(pAl + soA);
            *(float4*)(ldsb + 32768 + dst) = *(const float4*)(pBh + soB);
            *(float4*)(ldsb + 49152 + dst) = *(const float4*)(pBl + soB);
        }
        __syncthreads();
        #pragma unroll
        for (int kh = 0; kh < 2; kh++) {
            uint32_t ks = (uint32_t)((kh * 4 + lk) * 16);
            short8 fah[4], fal[4], fbh[2], fbl[2];
            #pragma unroll
            for (int m = 0; m < 4; m++) {
                uint32_t ob = arow[m] + (ks ^ axor[m]);
                fah[m] = *(const short8*)(ldsb + ob);
                fal[m] = *(const short8*)(ldsb + 16384 + ob);
            }
            #pragma unroll
            for (int n = 0; n < 2; n++) {
                uint32_t ob = brow[n] + (ks ^ bxor[n]);
                fbh[n] = *(const short8*)(ldsb + 32768 + ob);
                fbl[n] = *(const short8*)(ldsb + 49152 + ob);
            }
            #pragma unroll
            for (int m = 0; m < 4; m++)
                #pragma unroll
                for (int n = 0; n < 2; n++) {
                    acc[m][n] = __builtin_amdgcn_mfma_f32_16x16x32_bf16(fah[m], fbh[n], acc[m][n], 0, 0, 0);
                    acc[m][n] = __builtin_amdgcn_mfma_f32_16x16x32_bf16(fah[m], fbl[n], acc[m][n], 0, 0, 0);
                    acc[m][n] = __builtin_amdgcn_mfma_f32_16x16x32_bf16(fal[m], fbh[n], acc[m][n], 0, 0, 0);
                }
        }
        __syncthreads();
    }

    // epilogue: C col = lane&15, row = (lane>>4)*4 + reg (m89-verified)
    #pragma unroll
    for (int n = 0; n < 2; n++) {
        int gc = c0 + wc * 32 + n * 16 + lrow;
        float bb = (bias && gc < N) ? bias[gc] : 0.f;
        #pragma unroll
        for (int m = 0; m < 4; m++) {
            #pragma unroll
            for (int r = 0; r < 4; r++) {
                int gr = r0 + wr * 64 + m * 16 + lk * 4 + r;
                if (gr < NA && gc < N) {
                    float y = acc[m][n][r] + bb;
                    if (ACT == 1) y = y / (1.f + expf(-y));
                    if (ACT == 2) y = fmaxf(y, 0.f);
                    if (MODE == 0) {
                        Cf[(size_t)gr * N + gc] = y;
                    } else {
                        __bf16 h = (__bf16)y;
                        Ch[(size_t)gr * N + gc] = h;
                        Cl[(size_t)gr * N + gc] = (__bf16)(y - (float)h);
                    }
                }
            }
        }
    }
}

template<int ACT, int MODE>
__global__ __launch_bounds__(512, 4) void mgemm_kernel(
    const __bf16* __restrict__ Ah, const __bf16* __restrict__ Al,
    const __bf16* __restrict__ Bh, const __bf16* __restrict__ Bl,
    const float* __restrict__ bias, int K, int N,
    float* __restrict__ Cf, __bf16* __restrict__ Ch, __bf16* __restrict__ Cl) {
    __shared__ __attribute__((aligned(16))) char lds[65536];
    mgemm_body<ACT, MODE>(lds, Ah, Al, Bh, Bl, bias, K, N, blockIdx.y * 128, Cf, Ch, Cl);
}

// u_v / v_v batched: grid.z = 6 -> (mat = z/3 in {U,V}, d = z%3); fp32 out
__global__ __launch_bounds__(512, 4) void mgemm_uvvv_kernel(
    const __bf16* __restrict__ vBh, const __bf16* __restrict__ vBl,
    const __bf16* __restrict__ Uth, const __bf16* __restrict__ Utl,
    const __bf16* __restrict__ Vth, const __bf16* __restrict__ Vtl,
    float* __restrict__ uv, float* __restrict__ vv) {
    __shared__ __attribute__((aligned(16))) char lds[65536];
    int zz = blockIdx.z, d = zz % 3;
    const __bf16* Ah = vBh + (size_t)d * NF;
    const __bf16* Al = vBl + (size_t)d * NF;
    const __bf16* Bh = (zz < 3) ? Uth : Vth;
    const __bf16* Bl = (zz < 3) ? Utl : Vtl;
    float* Cf = ((zz < 3) ? uv : vv) + (size_t)d * NF;
    mgemm_body<0, 0>(lds, Ah, Al, Bh, Bl, nullptr, 128, 128, 0, Cf, nullptr, nullptr);
}

// Ws1 GEMM with fused "stack": A cols 0-127 = s (split, POST-message), cols
// 128-255 = vnorm computed on the fly from fp32 vv. K=256, N=128, silu, split out.
__global__ __launch_bounds__(512, 4) void mgemm_ws1_kernel(
    const __bf16* __restrict__ sh_, const __bf16* __restrict__ sl_,
    const float* __restrict__ vv,
    const __bf16* __restrict__ Bh, const __bf16* __restrict__ Bl,
    const float* __restrict__ bias,
    __bf16* __restrict__ Ch, __bf16* __restrict__ Cl) {
    __shared__ __attribute__((aligned(16))) char ldsb[65536];
    const int K = 256, N = 128;
    int tid = threadIdx.x;
    int w = tid >> 6, l = tid & 63;
    int r0 = blockIdx.x * 128;
    int srow = tid >> 3, sl = tid & 7;
    int wr = w >> 2, wc = w & 3;
    int lrow = l & 15, lk = l >> 4;
    uint32_t arow[4], axor[4], brow[2], bxor[2];
    #pragma unroll
    for (int m = 0; m < 4; m++) {
        int row = wr * 64 + m * 16 + lrow;
        arow[m] = (uint32_t)row * 128u; axor[m] = (uint32_t)((row & 7) << 4);
    }
    #pragma unroll
    for (int n = 0; n < 2; n++) {
        int row = wc * 32 + n * 16 + lrow;
        brow[n] = (uint32_t)row * 128u; bxor[n] = (uint32_t)((row & 7) << 4);
    }
    f32x4 acc[4][2];
    #pragma unroll
    for (int m = 0; m < 4; m++)
        #pragma unroll
        for (int n = 0; n < 2; n++) acc[m][n] = (f32x4){0.f, 0.f, 0.f, 0.f};

    for (int k0 = 0; k0 < K; k0 += 64) {
        #pragma unroll
        for (int t = 0; t < 2; t++) {
            int row = srow + t * 64;
            uint32_t dst = (uint32_t)row * 128u + (uint32_t)(((sl ^ (row & 7)) << 4));
            int ga = min(r0 + row, NA - 1);
            int gb = row;   // N=128 weight rows
            size_t soB = ((size_t)gb * K + k0 + sl * 8) * 2;
            *(float4*)(ldsb + 32768 + dst) = *(const float4*)((const char*)Bh + soB);
            *(float4*)(ldsb + 49152 + dst) = *(const float4*)((const char*)Bl + soB);
            if (k0 < 128) {
                size_t soA = ((size_t)ga * 128 + k0 + sl * 8) * 2;
                *(float4*)(ldsb + dst)         = *(const float4*)((const char*)sh_ + soA);
                *(float4*)(ldsb + 16384 + dst) = *(const float4*)((const char*)sl_ + soA);
            } else {
                int f0 = (k0 - 128) + sl * 8;
                size_t b = (size_t)ga * 128 + f0;
                float4 a0 = *(const float4*)(vv + b);
                float4 a1 = *(const float4*)(vv + b + 4);
                float4 b0 = *(const float4*)(vv + NF + b);
                float4 b1 = *(const float4*)(vv + NF + b + 4);
                float4 c0v = *(const float4*)(vv + 2 * NF + b);
                float4 c1v = *(const float4*)(vv + 2 * NF + b + 4);
                float xs[8] = {a0.x, a0.y, a0.z, a0.w, a1.x, a1.y, a1.z, a1.w};
                float ys[8] = {b0.x, b0.y, b0.z, b0.w, b1.x, b1.y, b1.z, b1.w};
                float zs[8] = {c0v.x, c0v.y, c0v.z, c0v.w, c1v.x, c1v.y, c1v.z, c1v.w};
                union { short8 s; float4 q; } hi, lo;
                #pragma unroll
                for (int k = 0; k < 8; k++) {
                    float vn = sqrtf(xs[k] * xs[k] + ys[k] * ys[k] + zs[k] * zs[k] + 1e-15f);
                    __bf16 h = (__bf16)vn;
                    hi.s[k] = *(short*)&h;
                    __bf16 lo_b = (__bf16)(vn - (float)h);
                    lo.s[k] = *(short*)&lo_b;
                }
                *(float4*)(ldsb + dst)         = hi.q;
                *(float4*)(ldsb + 16384 + dst) = lo.q;
            }
        }
        __syncthreads();
        #pragma unroll
        for (int kh = 0; kh < 2; kh++) {
            uint32_t ks = (uint32_t)((kh * 4 + lk) * 16);
            short8 fah[4], fal[4], fbh[2], fbl[2];
            #pragma unroll
            for (int m = 0; m < 4; m++) {
                uint32_t ob = arow[m] + (ks ^ axor[m]);
                fah[m] = *(const short8*)(ldsb + ob);
                fal[m] = *(const short8*)(ldsb + 16384 + ob);
            }
            #pragma unroll
            for (int n = 0; n < 2; n++) {
                uint32_t ob = brow[n] + (ks ^ bxor[n]);
                fbh[n] = *(const short8*)(ldsb + 32768 + ob);
                fbl[n] = *(const short8*)(ldsb + 49152 + ob);
            }
            #pragma unroll
            for (int m = 0; m < 4; m++)
                #pragma unroll
                for (int n = 0; n < 2; n++) {
                    acc[m][n] = __builtin_amdgcn_mfma_f32_16x16x32_bf16(fah[m], fbh[n], acc[m][n], 0, 0, 0);
                    acc[m][n] = __builtin_amdgcn_mfma_f32_16x16x32_bf16(fah[m], fbl[n], acc[m][n], 0, 0, 0);
                    acc[m][n] = __builtin_amdgcn_mfma_f32_16x16x32_bf16(fal[m], fbh[n], acc[m][n], 0, 0, 0);
                }
        }
        __syncthreads();
    }
    #pragma unroll
    for (int n = 0; n < 2; n++) {
        int gc = wc * 32 + n * 16 + lrow;
        float bb = bias[gc];
        #pragma unroll
        for (int m = 0; m < 4; m++) {
            #pragma unroll
            for (int r = 0; r < 4; r++) {
                int gr = r0 + wr * 64 + m * 16 + lk * 4 + r;
                if (gr < NA) {
                    float y = acc[m][n][r] + bb;
                    y = y / (1.f + expf(-y));
                    __bf16 h = (__bf16)y;
                    Ch[(size_t)gr * N + gc] = h;
                    Cl[(size_t)gr * N + gc] = (__bf16)(y - (float)h);
                }
            }
        }
    }
}

// GEMM with fused UPDATE in A-staging: A[row][f] = split of
// ns = s[row,f] + (sum_d uv*vv)*a_sv + a_ss   (the update_kernel math).
// sBuf is READ unconditionally (must be valid!); WRST guards the vA/sBuf
// writes AND clamped duplicate rows never write (race-free).
// K=128 fixed; NOUT = 128 (W1, silu) or 64 (ro_W1, silu). Split-bf16 out.
template<int NOUT, int WRST>
__global__ __launch_bounds__(512, 4) void mgemm_upd_kernel(
    const float* __restrict__ spl, const float* __restrict__ uv, const float* __restrict__ vv,
    const __bf16* __restrict__ vBh, const __bf16* __restrict__ vBl,
    const __bf16* __restrict__ Bh, const __bf16* __restrict__ Bl,
    const float* __restrict__ bias,
    float* __restrict__ vA, float* __restrict__ sBuf,
    __bf16* __restrict__ Ch, __bf16* __restrict__ Cl) {
    __shared__ __attribute__((aligned(16))) char ldsb[65536];
    const int K = 128;
    int tid = threadIdx.x;
    int w = tid >> 6, l = tid & 63;
    int r0 = blockIdx.x * 128;
    int srow = tid >> 3, sl = tid & 7;
    int wr = w >> 2, wc = w & 3;
    int lrow = l & 15, lk = l >> 4;
    uint32_t arow[4], axor[4], brow[2], bxor[2];
    #pragma unroll
    for (int m = 0; m < 4; m++) {
        int row = wr * 64 + m * 16 + lrow;
        arow[m] = (uint32_t)row * 128u; axor[m] = (uint32_t)((row & 7) << 4);
    }
    #pragma unroll
    for (int n = 0; n < 2; n++) {
        int row = wc * 32 + n * 16 + lrow;
        brow[n] = (uint32_t)row * 128u; bxor[n] = (uint32_t)((row & 7) << 4);
    }
    f32x4 acc[4][2];
    #pragma unroll
    for (int m = 0; m < 4; m++)
        #pragma unroll
        for (int n = 0; n < 2; n++) acc[m][n] = (f32x4){0.f, 0.f, 0.f, 0.f};

    for (int k0 = 0; k0 < K; k0 += 64) {
        #pragma unroll
        for (int t = 0; t < 2; t++) {
            int row = srow + t * 64;
            uint32_t dst = (uint32_t)row * 128u + (uint32_t)(((sl ^ (row & 7)) << 4));
            int gr0 = r0 + row;
            bool real = gr0 < NA;
            int ga = real ? gr0 : (NA - 1);
            int gb = min(row, NOUT - 1);
            size_t soB = ((size_t)gb * K + k0 + sl * 8) * 2;
            *(float4*)(ldsb + 32768 + dst) = *(const float4*)((const char*)Bh + soB);
            *(float4*)(ldsb + 49152 + dst) = *(const float4*)((const char*)Bl + soB);

            int f0 = k0 + sl * 8;
            const float* sp = spl + (size_t)ga * 384;
            float4 av0 = *(const float4*)(sp + f0);
            float4 av1 = *(const float4*)(sp + f0 + 4);
            float avv[8] = {av0.x, av0.y, av0.z, av0.w, av1.x, av1.y, av1.z, av1.w};
            float dot[8] = {0.f, 0.f, 0.f, 0.f, 0.f, 0.f, 0.f, 0.f};
            size_t eb = (size_t)ga * 128 + f0;
            #pragma unroll
            for (int d = 0; d < 3; d++) {
                float4 u0 = *(const float4*)(uv + d * NF + eb);
                float4 u1 = *(const float4*)(uv + d * NF + eb + 4);
                float4 w0 = *(const float4*)(vv + d * NF + eb);
                float4 w1 = *(const float4*)(vv + d * NF + eb + 4);
                bf16x8 bh = *(const bf16x8*)(vBh + d * NF + eb);
                bf16x8 bl = *(const bf16x8*)(vBl + d * NF + eb);
                float uu[8] = {u0.x, u0.y, u0.z, u0.w, u1.x, u1.y, u1.z, u1.w};
                float ww[8] = {w0.x, w0.y, w0.z, w0.w, w1.x, w1.y, w1.z, w1.w};
                float nv[8];
                #pragma unroll
                for (int k = 0; k < 8; k++) {
                    float vb = (float)bh[k] + (float)bl[k];
                    nv[k] = vb + uu[k] * avv[k];
                    dot[k] += uu[k] * ww[k];
                }
                if (WRST && real) {
                    float* vp = vA + (size_t)ga * 384 + d * 128 + f0;
                    *(float4*)(vp)     = make_float4(nv[0], nv[1], nv[2], nv[3]);
                    *(float4*)(vp + 4) = make_float4(nv[4], nv[5], nv[6], nv[7]);
                }
            }
            float4 as0 = *(const float4*)(sp + 128 + f0);
            float4 as1 = *(const float4*)(sp + 128 + f0 + 4);
            float4 az0 = *(const float4*)(sp + 256 + f0);
            float4 az1 = *(const float4*)(sp + 256 + f0 + 4);
            float4 sv0 = *(const float4*)(sBuf + eb);
            float4 sv1 = *(const float4*)(sBuf + eb + 4);
            float asv[8] = {as0.x, as0.y, as0.z, as0.w, as1.x, as1.y, as1.z, as1.w};
            float ass[8] = {az0.x, az0.y, az0.z, az0.w, az1.x, az1.y, az1.z, az1.w};
            float sv[8]  = {sv0.x, sv0.y, sv0.z, sv0.w, sv1.x, sv1.y, sv1.z, sv1.w};
            float ns[8];
            union { short8 s; float4 q; } hi, lo;
            #pragma unroll
            for (int k = 0; k < 8; k++) {
                ns[k] = sv[k] + dot[k] * asv[k] + ass[k];
                __bf16 h = (__bf16)ns[k];
                hi.s[k] = *(short*)&h;
                __bf16 lo_b = (__bf16)(ns[k] - (float)h);
                lo.s[k] = *(short*)&lo_b;
            }
            if (WRST && real) {
                *(float4*)(sBuf + eb)     = make_float4(ns[0], ns[1], ns[2], ns[3]);
                *(float4*)(sBuf + eb + 4) = make_float4(ns[4], ns[5], ns[6], ns[7]);
            }
            *(float4*)(ldsb + dst)         = hi.q;
            *(float4*)(ldsb + 16384 + dst) = lo.q;
        }
        __syncthreads();
        #pragma unroll
        for (int kh = 0; kh < 2; kh++) {
            uint32_t ks = (uint32_t)((kh * 4 + lk) * 16);
            short8 fah[4], fal[4], fbh[2], fbl[2];
            #pragma unroll
            for (int m = 0; m < 4; m++) {
                uint32_t ob = arow[m] + (ks ^ axor[m]);
                fah[m] = *(const short8*)(ldsb + ob);
                fal[m] = *(const short8*)(ldsb + 16384 + ob);
            }
            #pragma unroll
            for (int n = 0; n < 2; n++) {
                uint32_t ob = brow[n] + (ks ^ bxor[n]);
                fbh[n] = *(const short8*)(ldsb + 32768 + ob);
                fbl[n] = *(const short8*)(ldsb + 49152 + ob);
            }
            #pragma unroll
            for (int m = 0; m < 4; m++)
                #pragma unroll
                for (int n = 0; n < 2; n++) {
                    acc[m][n] = __builtin_amdgcn_mfma_f32_16x16x32_bf16(fah[m], fbh[n], acc[m][n], 0, 0, 0);
                    acc[m][n] = __builtin_amdgcn_mfma_f32_16x16x32_bf16(fah[m], fbl[n], acc[m][n], 0, 0, 0);
                    acc[m][n] = __builtin_amdgcn_mfma_f32_16x16x32_bf16(fal[m], fbh[n], acc[m][n], 0, 0, 0);
                }
        }
        __syncthreads();
    }
    // epilogue: silu + split-bf16 out, guard gc < NOUT
    #pragma unroll
    for (int n = 0; n < 2; n++) {
        int gc = wc * 32 + n * 16 + lrow;
        float bb = (gc < NOUT) ? bias[gc] : 0.f;
        #pragma unroll
        for (int m = 0; m < 4; m++) {
            #pragma unroll
            for (int r = 0; r < 4; r++) {
                int gr = r0 + wr * 64 + m * 16 + lk * 4 + r;
                if (gr < NA && gc < NOUT) {
                    float y = acc[m][n][r] + bb;
                    y = y / (1.f + expf(-y));
                    __bf16 h = (__bf16)y;
                    Ch[(size_t)gr * NOUT + gc] = h;
                    Cl[(size_t)gr * NOUT + gc] = (__bf16)(y - (float)h);
                }
            }
        }
    }
}

// ---------------------------------------------------------------- message + aggregation
// one atom per 128-thread block; v state interleaved [n][3][128];
// refreshes sh_/sl_ (split of post-message s) for the fused Ws1 gemm.
__global__ __launch_bounds__(128) void msg_kernel(
    const float* __restrict__ phi, const float* __restrict__ edc,
    const int* __restrict__ jc, const int* __restrict__ offs,
    const float* __restrict__ Wd, const float* __restrict__ bd,
    const float* __restrict__ vin, float* __restrict__ s,
    __bf16* __restrict__ sh_, __bf16* __restrict__ sl_,
    __bf16* __restrict__ vBh, __bf16* __restrict__ vBl) {
    int i = blockIdx.x;
    int f = threadIdx.x;
    float wd0[20], wd1[20], wd2[20];
    #pragma unroll
    for (int k = 0; k < 20; k++) {
        wd0[k] = Wd[k * 384 + f];
        wd1[k] = Wd[k * 384 + 128 + f];
        wd2[k] = Wd[k * 384 + 256 + f];
    }
    float b0 = bd[f], b1 = bd[128 + f], b2 = bd[256 + f];
    float accS = 0.f, aV0 = 0.f, aV1 = 0.f, aV2 = 0.f;
    int p0 = offs[i], p1 = offs[i + 1];
    for (int p = p0; p < p1; ++p) {
        int j = jc[p];
        const float4* ed = (const float4*)(edc + (size_t)p * 24);
        float4 q0 = ed[0], q1 = ed[1], q2 = ed[2], q3 = ed[3], q4 = ed[4], q5 = ed[5];
        float fc = q0.x, ux = q0.y, uy = q0.z, uz = q0.w;
        float rb[20];
        rb[0]=q1.x; rb[1]=q1.y; rb[2]=q1.z; rb[3]=q1.w;
        rb[4]=q2.x; rb[5]=q2.y; rb[6]=q2.z; rb[7]=q2.w;
        rb[8]=q3.x; rb[9]=q3.y; rb[10]=q3.z; rb[11]=q3.w;
        rb[12]=q4.x; rb[13]=q4.y; rb[14]=q4.z; rb[15]=q4.w;
        rb[16]=q5.x; rb[17]=q5.y; rb[18]=q5.z; rb[19]=q5.w;
        float w0 = b0 * fc, w1 = b1 * fc, w2 = b2 * fc;
        #pragma unroll
        for (int k = 0; k < 20; k++) {
            w0 += rb[k] * wd0[k];
            w1 += rb[k] * wd1[k];
            w2 += rb[k] * wd2[k];
        }
        const float* pj = phi + (size_t)j * 384;
        float i0 = pj[f] * w0, i1 = pj[128 + f] * w1, i2 = pj[256 + f] * w2;
        const float* vj = vin + (size_t)j * 384;
        accS += i1;
        aV0 += i2 * ux + i0 * vj[f];
        aV1 += i2 * uy + i0 * vj[128 + f];
        aV2 += i2 * uz + i0 * vj[256 + f];
    }
    size_t ib = (size_t)i * F + f;
    float ns = s[ib] + accS;
    s[ib] = ns;
    __bf16 hs = (__bf16)ns;
    sh_[ib] = hs; sl_[ib] = (__bf16)(ns - (float)hs);
    const float* vi = vin + (size_t)i * 384;
    float o0 = vi[f] + aV0;
    float o1 = vi[128 + f] + aV1;
    float o2 = vi[256 + f] + aV2;
    __bf16 h0 = (__bf16)o0, h1 = (__bf16)o1, h2 = (__bf16)o2;
    vBh[ib] = h0;            vBl[ib] = (__bf16)(o0 - (float)h0);
    vBh[NF + ib] = h1;       vBl[NF + ib] = (__bf16)(o1 - (float)h1);
    vBh[2 * NF + ib] = h2;   vBl[2 * NF + ib] = (__bf16)(o2 - (float)h2);
}

// ---------------------------------------------------------------- head
__global__ __launch_bounds__(256) void head_kernel(const float* __restrict__ h,
                                                   const float* __restrict__ Wo,
                                                   const float* __restrict__ bo,
                                                   float* __restrict__ out) {
    int n = blockIdx.x * 4 + (threadIdx.x >> 6);
    int lane = threadIdx.x & 63;
    if (n >= NA) return;
    float p = h[(size_t)n * 128 + lane] * Wo[lane] + h[(size_t)n * 128 + 64 + lane] * Wo[64 + lane];
    #pragma unroll
    for (int o = 32; o > 0; o >>= 1) p += __shfl_down(p, o);
    if (lane == 0) out[n] = p + bo[0];
}

// ---------------------------------------------------------------- host
extern "C" void kernel_launch(void* const* d_in, const int* in_sizes, int n_in,
                              void* d_out, int out_size, void* d_ws, size_t ws_size,
                              hipStream_t stream) {
    const float* xyz    = (const float*)d_in[0];
    const int*   z      = (const int*)d_in[1];
    const int*   nbrs   = (const int*)d_in[2];
    const float* embed  = (const float*)d_in[3];
    const float* msg_W1 = (const float*)d_in[4];
    const float* msg_b1 = (const float*)d_in[5];
    const float* msg_W2 = (const float*)d_in[6];
    const float* msg_b2 = (const float*)d_in[7];
    const float* msg_Wd = (const float*)d_in[8];
    const float* msg_bd = (const float*)d_in[9];
    const float* upd_U  = (const float*)d_in[10];
    const float* upd_V  = (const float*)d_in[11];
    const float* upd_Ws1= (const float*)d_in[12];
    const float* upd_bs1= (const float*)d_in[13];
    const float* upd_Ws2= (const float*)d_in[14];
    const float* upd_bs2= (const float*)d_in[15];
    const float* ro_W1  = (const float*)d_in[16];
    const float* ro_b1  = (const float*)d_in[17];
    const float* ro_W2  = (const float*)d_in[18];
    const float* ro_b2  = (const float*)d_in[19];
    const float* fc_W1  = (const float*)d_in[20];
    const float* fc_b1  = (const float*)d_in[21];
    const float* fc_W2  = (const float*)d_in[22];
    const float* fc_b2  = (const float*)d_in[23];
    const float* fc_Wo  = (const float*)d_in[24];
    const float* fc_bo  = (const float*)d_in[25];
    float* out = (float*)d_out;

    char* ws = (char*)d_ws;
    size_t off = 0;
    auto alloc = [&](size_t nbytes) -> char* {
        char* p = ws + off;
        off += (nbytes + 255) / 256 * 256;
        return p;
    };
    // total ~240.6 MB (R5/R7/R9/R11 passed at this size; 271 faulted)
    float*  edc   = (float*)alloc((size_t)NE * 24 * 4);
    float*  s     = (float*)alloc((size_t)NA * F * 4);
    __bf16* sh_   = (__bf16*)alloc((size_t)NA * F * 2);
    __bf16* sl_   = (__bf16*)alloc((size_t)NA * F * 2);
    float*  vA    = (float*)alloc((size_t)3 * NF * 4);     // interleaved [n][3][128]
    __bf16* vBh   = (__bf16*)alloc((size_t)3 * NF * 2);
    __bf16* vBl   = (__bf16*)alloc((size_t)3 * NF * 2);
    float*  phi   = (float*)alloc((size_t)NA * 384 * 4);   // also spl + readout t4
    __bf16* hid_h = (__bf16*)alloc((size_t)NA * F * 2);    // also t1h
    __bf16* hid_l = (__bf16*)alloc((size_t)NA * F * 2);    // also t1l
    float*  uv    = (float*)alloc((size_t)3 * NF * 4);     // also geometry temp
    float*  vv    = (float*)alloc((size_t)3 * NF * 4);
    __bf16* stkh  = (__bf16*)alloc((size_t)NA * 256 * 2);  // readout t2h
    __bf16* stkl  = (__bf16*)alloc((size_t)NA * 256 * 2);  // readout t2l
    __bf16* wt_h  = (__bf16*)alloc((size_t)WTOT * 2);
    __bf16* wt_l  = (__bf16*)alloc((size_t)WTOT * 2);
    int* act  = (int*)alloc((size_t)NE * 4);
    int* cnt2 = (int*)alloc((size_t)2 * NA * 4);           // cnt | cur, one memset
    int* offs = (int*)alloc((size_t)(NA + 1) * 4);
    int* jc   = (int*)alloc((size_t)NE * 4);
    int* cnt = cnt2;
    int* cur = cnt2 + NA;

    float* edata = uv;                 // geometry temp (dead before uv first written)
    __bf16* t1h = hid_h, *t1l = hid_l; // readout temps (dead after layers)
    __bf16* t2h = stkh,  *t2l = stkl;
    __bf16* t3h = sh_,   *t3l = sl_;   // sh_ dead after readout gemm2 chain starts
    float*  t4  = phi;

    // geometry + active-edge CSR
    hipMemsetAsync(cnt2, 0, (size_t)2 * NA * 4, stream);
    geom_kernel<<<(NE + 255) / 256, 256, 0, stream>>>(xyz, nbrs, edata, act, cnt);
    scan_kernel<<<1, 1024, 0, stream>>>(cnt, offs);
    fill_kernel<<<(NE + 255) / 256, 256, 0, stream>>>(nbrs, act, offs, cur, edata, jc, edc);

    // weights + init state
    wconv_kernel<<<(WTOT + 255) / 256, 256, 0, stream>>>(msg_W1, msg_W2, upd_U, upd_V,
                                                         upd_Ws1, upd_Ws2, ro_W1, ro_W2,
                                                         fc_W1, fc_W2, wt_h, wt_l);
    hipMemsetAsync(vA, 0, (size_t)3 * NF * 4, stream);
    embed_kernel<<<(NA * F + 255) / 256, 256, 0, stream>>>(z, embed, s, sh_, sl_);

    const int GX = (NA + 127) / 128;  // 157
    for (int l = 0; l < 3; l++) {
        const __bf16* w1h = wt_h + (size_t)l * WSEG,          *w1l = wt_l + (size_t)l * WSEG;
        const __bf16* w2h = w1h + 16384,  *w2l = w1l + 16384;
        const __bf16* uh  = w1h + 65536,  *ul  = w1l + 65536;
        const __bf16* vh  = w1h + 81920,  *vl  = w1l + 81920;
        const __bf16* s1h = w1h + 98304,  *s1l = w1l + 98304;
        const __bf16* s2h = w1h + 131072, *s2l = w1l + 131072;

        if (l == 0) {
            mgemm_kernel<1, 1><<<dim3(GX, 1), 512, 0, stream>>>(sh_, sl_, w1h, w1l,
                msg_b1 + (size_t)l * 128, 128, 128, nullptr, hid_h, hid_l);
        } else {
            // fused: previous layer's update + this layer's W1
            mgemm_upd_kernel<128, 1><<<dim3(GX, 1), 512, 0, stream>>>(
                phi, uv, vv, vBh, vBl, w1h, w1l, msg_b1 + (size_t)l * 128,
                vA, s, hid_h, hid_l);
        }
        mgemm_kernel<0, 0><<<dim3(GX, 3), 512, 0, stream>>>(hid_h, hid_l, w2h, w2l,
            msg_b2 + (size_t)l * 384, 128, 384, phi, nullptr, nullptr);
        msg_kernel<<<NA, 128, 0, stream>>>(phi, edc, jc, offs,
            msg_Wd + (size_t)l * 20 * 384, msg_bd + (size_t)l * 384,
            vA, s, sh_, sl_, vBh, vBl);
        mgemm_uvvv_kernel<<<dim3(GX, 1, 6), 512, 0, stream>>>(vBh, vBl, uh, ul, vh, vl, uv, vv);
        mgemm_ws1_kernel<<<dim3(GX, 1), 512, 0, stream>>>(sh_, sl_, vv, s1h, s1l,
            upd_bs1 + (size_t)l * 128, hid_h, hid_l);
        mgemm_kernel<0, 0><<<dim3(GX, 3), 512, 0, stream>>>(hid_h, hid_l, s2h, s2l,
            upd_bs2 + (size_t)l * 384, 128, 384, phi, nullptr, nullptr);
        // update fused into next W1 / readout gemm1 — no update_kernel dispatch
    }

    // readout: gemm1 fused with the final update (WRST=0: vA/s writes dead;
    // sBuf=s still READ by the update math — must be a valid pointer)
    const __bf16* roh = wt_h + WRO, *rol = wt_l + WRO;
    mgemm_upd_kernel<64, 0><<<dim3(GX, 1), 512, 0, stream>>>(
        phi, uv, vv, vBh, vBl, roh, rol, ro_b1, nullptr, s, t1h, t1l);
    mgemm_kernel<0, 1><<<dim3(GX, 1), 512, 0, stream>>>(t1h, t1l, roh + 8192, rol + 8192,
        ro_b2, 64, 64, nullptr, t2h, t2l);
    mgemm_kernel<2, 1><<<dim3(GX, 1), 512, 0, stream>>>(t2h, t2l, roh + 12288, rol + 12288,
        fc_b1, 64, 128, nullptr, t3h, t3l);
    mgemm_kernel<2, 0><<<dim3(GX, 1), 512, 0, stream>>>(t3h, t3l, roh + 20480, rol + 20480,
        fc_b2, 128, 128, t4, nullptr, nullptr);
    head_kernel<<<NA / 4, 256, 0, stream>>>(t4, fc_Wo, fc_bo, out);
}